// Round 9
// baseline (10439.049 us; speedup 1.0000x reference)
//
#include <hip/hip_runtime.h>
#include <math.h>

// LVCBlock forward, MI355X (gfx950).
// Shapes: B=16, CIN=32, CCOND=100, Lc=512, HOP=8, T=4096, HID=64, NL=4, K=3, COUT=64.
// ALL inputs and the output are float32.
//
// R9 vs R8 (passed, k_lvc 591us, VALUBusy 53%, FMA floor 123us):
// Phase 1 (kernel-head GEMM) moves to mfma_f32_16x16x32_bf16 with SPLIT
// PRECISION: w = w_hi + w_lo (bf16 pair, rel err 2^-18), h = h_hi + h_lo,
// 3 MFMA products (hi*hi + lo*hi + hi*lo), fp32 accumulate. Kern rel err
// ~2^-16; the network's ~30x error amplification (diagnosed R3-R6: bf16
// single -> 0.34-0.45 absmax) leaves ~1e-3, far under the 0.117 threshold.
// Geometry = R8's (512 blocks x 512 thr, quarter-split o-chunks, per-pass
// kc): pass = 64 rows = 4 m-tiles x 4 n-tiles; wave owns 1 n-tile + 2
// m-tiles; h fragments built once per block from fp32 LDS stage whose
// memory is reused for kc (union, 49.4 KB -> 2 blocks/CU @ lb(512,4)).
// Weights packed per layer to hi/lo bf16 in MFMA A-fragment order.

#define DEV __device__ __forceinline__

typedef unsigned short ushort;
typedef unsigned int uint;
typedef __attribute__((ext_vector_type(8))) short short8;   // 8 bf16 (4 VGPRs)
typedef __attribute__((ext_vector_type(4))) float f32x4;

DEV float lrelu(float x) { return x > 0.f ? x : 0.2f * x; }

DEV ushort f2bf(float f) {                     // fp32 -> bf16 bits, RNE
    uint u = __float_as_uint(f);
    return (ushort)((u + 0x7fffu + ((u >> 16) & 1u)) >> 16);
}
DEV float bf2f(ushort b) { return __uint_as_float(((uint)b) << 16); }

// ---------------- kernel predictor: input conv (100->64, k=5, pad=2) + lrelu
__global__ void k_pred_in(const float* __restrict__ c, const float* __restrict__ w,
                          const float* __restrict__ bias, float* __restrict__ h) {
    int idx = blockIdx.x * 256 + threadIdx.x;          // 16*64*512
    int l = idx & 511, co = (idx >> 9) & 63, b = idx >> 15;
    float acc = bias[co];
    for (int ci = 0; ci < 100; ++ci) {
        const float* crow = c + (b * 100 + ci) * 512;
        const float* wrow = w + (co * 100 + ci) * 5;
#pragma unroll
        for (int j = 0; j < 5; ++j) {
            int p = l + j - 2;
            if (p >= 0 && p < 512) acc += crow[p] * wrow[j];
        }
    }
    h[idx] = lrelu(acc);
}

// ---------------- residual conv (64->64, k=3, pad=1) + lrelu, optional accumulate
__global__ void k_res(const float* __restrict__ src, const float* __restrict__ w,
                      const float* __restrict__ bias, float* __restrict__ dst,
                      const float* __restrict__ accum) {
    int idx = blockIdx.x * 256 + threadIdx.x;          // 16*64*512
    int l = idx & 511, co = (idx >> 9) & 63, b = idx >> 15;
    float acc = bias[co];
    for (int ci = 0; ci < 64; ++ci) {
        const float* s = src + (b * 64 + ci) * 512;
        const float* wr = w + (co * 64 + ci) * 3;
#pragma unroll
        for (int j = 0; j < 3; ++j) {
            int p = l + j - 1;
            if (p >= 0 && p < 512) acc += s[p] * wr[j];
        }
    }
    float v = lrelu(acc);
    dst[idx] = accum ? accum[idx] + v : v;
}

// ---------------- bias head, ONE layer's 64 channels (k=3, pad=1)
__global__ void k_head(const float* __restrict__ h, const float* __restrict__ w,
                       const float* __restrict__ bias, float* __restrict__ out, int layer) {
    int idx = blockIdx.x * 256 + threadIdx.x;          // 16*64*512
    int l = idx & 511, o = (idx >> 9) & 63, b = idx >> 15;
    int ch = layer * 64 + o;
    float acc = bias[ch];
    for (int ci = 0; ci < 64; ++ci) {
        const float* s = h + (b * 64 + ci) * 512;
        const float* wr = w + (ch * 64 + ci) * 3;
#pragma unroll
        for (int j = 0; j < 3; ++j) {
            int p = l + j - 1;
            if (p >= 0 && p < 512) acc += s[p] * wr[j];
        }
    }
    out[idx] = acc;   // (b*64+o)*512 + l
}

// ---------------- convt_pre: lrelu then ConvTranspose1d(32->32, k=16, s=8, p=4)
__global__ void k_convt(const float* __restrict__ x, const float* __restrict__ w,
                        const float* __restrict__ bias, float* __restrict__ xx) {
    int idx = blockIdx.x * 256 + threadIdx.x;          // 16*32*4096
    int t = idx & 4095, co = (idx >> 12) & 31, b = idx >> 17;
    int m0 = (t + 4) & 7, s0 = (t + 4) >> 3;
    float acc = bias[co];
    for (int ci = 0; ci < 32; ++ci) {
        const float* xr = x + (b * 32 + ci) * 512;
        const float* wr = w + (ci * 32 + co) * 16;
        if (s0 < 512) acc += lrelu(xr[s0]) * wr[m0];
        if (s0 >= 1) acc += lrelu(xr[s0 - 1]) * wr[m0 + 8];
    }
    xx[idx] = acc;
}

// ---------------- dilated conv block: lrelu(conv(lrelu(xx), k=3, dil, pad=dil))
__global__ void k_cblock(const float* __restrict__ xx, const float* __restrict__ w,
                         const float* __restrict__ bias, float* __restrict__ cb,
                         int layer, int dil) {
    int idx = blockIdx.x * 256 + threadIdx.x;          // 16*32*4096
    int t = idx & 4095, ci = (idx >> 12) & 31, b = idx >> 17;
    float acc = bias[layer * 32 + ci];
    for (int c2 = 0; c2 < 32; ++c2) {
        const float* s = xx + (b * 32 + c2) * 4096;
        const float* wr = w + ((layer * 32 + ci) * 32 + c2) * 3;
#pragma unroll
        for (int j = 0; j < 3; ++j) {
            int p = t + (j - 1) * dil;
            if (p >= 0 && p < 4096) acc += lrelu(s[p]) * wr[j];
        }
    }
    cb[idx] = lrelu(acc);
}

// ---------------- weight pack (ONE layer): fp32 -> hi/lo bf16, MFMA A-frag order.
// Flat: (((c*24 + MT)*6 + ks)*64 + lane)*8 + j ; A[m=lane&15][k=quad*8+j].
// Row r = MT*16 + m; ik = r>>2 (=i*3+kk), oc = r&3;
// o = 32*(oc&1) + 2*c + (oc>>1); ch = (i*64+o)*3 + kk.
__global__ void k_pack_w2(const float* __restrict__ ker_w, ushort* __restrict__ Whi,
                          ushort* __restrict__ Wlo, int layer) {
    int g = blockIdx.x * 256 + threadIdx.x;            // < 147456
    int lane = g & 63;
    int g2 = g >> 6;
    int ks = g2 % 6;  int g3 = g2 / 6;
    int mt = g3 % 24; int c = g3 / 24;                 // c in [0,16)
    int m = lane & 15, quad = lane >> 4;
    int r = mt * 16 + m;
    int ik = r >> 2, oc = r & 3;
    int i = ik / 3, kk = ik - i * 3;
    int o = 32 * (oc & 1) + 2 * c + (oc >> 1);
    int ch = (i * 64 + o) * 3 + kk;
    const float* src = ker_w + ((size_t)(layer * 6144 + ch)) * 192 + ks * 32 + quad * 8;
    uint uh[4], ul[4];
#pragma unroll
    for (int t = 0; t < 4; ++t) {
        float f0 = src[2 * t], f1 = src[2 * t + 1];
        ushort h0 = f2bf(f0), h1 = f2bf(f1);
        ushort l0 = f2bf(f0 - bf2f(h0)), l1 = f2bf(f1 - bf2f(h1));
        uh[t] = (uint)h0 | ((uint)h1 << 16);
        ul[t] = (uint)l0 | ((uint)l1 << 16);
    }
    *reinterpret_cast<uint4*>(Whi + (size_t)g * 8) = make_uint4(uh[0], uh[1], uh[2], uh[3]);
    *reinterpret_cast<uint4*>(Wlo + (size_t)g * 8) = make_uint4(ul[0], ul[1], ul[2], ul[3]);
}

// ---------------- bias pack (ONE layer): ker_b -> chunk-row order Bpk[c][r]
__global__ void k_pack_b(const float* __restrict__ ker_b, float* __restrict__ Bpk,
                         int layer) {
    int idx = blockIdx.x * 256 + threadIdx.x;          // < 6144
    int c = idx / 384, r = idx - c * 384;
    int ik = r >> 2, oc = r & 3;
    int i = ik / 3, kk = ik - i * 3;
    int o = 32 * (oc & 1) + 2 * c + (oc >> 1);
    int ch = (i * 64 + o) * 3 + kk;
    Bpk[idx] = ker_b[layer * 6144 + ch];
}

// ---------------- fused: split-precision MFMA kernel-head GEMM + einsum + gate
// Block = (b, 64-l tile, quarter). Chunk c: o in {2c,2c+1,32+2c,32+2c+1}.
// Per chunk 6 passes of 64 rows (4 m-tiles x 4 n-tiles); wave w: n-tile w>>1,
// m-tiles (w&1)*2+{0,1}. 3-product MFMA chain per ks. kc pass-buffered in the
// LDS region that held the fp32 h stage (dead after frag build).
__global__ __launch_bounds__(512, 4) void
k_lvc(const float* __restrict__ h, const float* __restrict__ cb,
      const float* __restrict__ kbL, const ushort* __restrict__ Whi,
      const ushort* __restrict__ Wlo, const float* __restrict__ Bpk,
      float* __restrict__ xx) {
    __shared__ float smem[12352];       // phase A: Ht32[n*193+cj]; phase B: kc
    float* Ht32 = smem;
    float* kc = smem;                   // kc[(ik_local*64 + n)*4 + oc], 4096 floats

    int tid = threadIdx.x;
    int qtr = blockIdx.x & 3;
    int lt = (blockIdx.x >> 2) & 7;
    int b = blockIdx.x >> 5;
    int l0 = lt * 64;

    // ---- stage h window fp32: Ht32[n*193+cj] = h[b, cj/3, l0+n + cj%3 - 1]
    for (int v = tid; v < 192 * 64; v += 512) {
        int cj = v >> 6, n = v & 63;
        int ci = cj / 3, jt = cj - ci * 3;
        int p = l0 + n + jt - 1;
        Ht32[n * 193 + cj] = (p >= 0 && p < 512) ? h[(b * 64 + ci) * 512 + p] : 0.f;
    }
    __syncthreads();

    // ---- build B fragments (h hi/lo), once per block: wave w owns nt = w>>1
    int wave = tid >> 6, lane = tid & 63;
    int n16 = lane & 15, quad = lane >> 4;
    int nt = wave >> 1;
    int nloc = nt * 16 + n16;
    short8 bhi[6], blo[6];
#pragma unroll
    for (int ks = 0; ks < 6; ++ks) {
        short8 vh, vl;
#pragma unroll
        for (int j = 0; j < 8; ++j) {
            float f = Ht32[nloc * 193 + ks * 32 + quad * 8 + j];
            ushort hi = f2bf(f);
            ushort lo = f2bf(f - bf2f(hi));
            vh[j] = (short)hi;
            vl[j] = (short)lo;
        }
        bhi[ks] = vh;
        blo[ks] = vl;
    }
    __syncthreads();                    // Ht32 dead; smem becomes kc

    int mt0 = (wave & 1) * 2;           // this wave's 2 m-tiles (local)
    int h8 = tid & 7, n2 = tid >> 3;    // phase-2 coords
    int tglob = (l0 + n2) * 8 + h8;
    int lg = l0 + n2;
    const float* cbb = cb + b * 32 * 4096;
    const float* kbb = kbL + b * 64 * 512;
    float* xxb = xx + b * 32 * 4096;

    for (int c = qtr * 4; c < qtr * 4 + 4; ++c) {
        float a0 = 0.f, a1 = 0.f, a2 = 0.f, a3 = 0.f;   // phase-2 partials
        for (int p = 0; p < 6; ++p) {
            // ---- phase 1: 2 MFMA tile-jobs per wave
#pragma unroll
            for (int jj = 0; jj < 2; ++jj) {
                int mtl = mt0 + jj;                      // local m-tile in [0,4)
                int MT = p * 4 + mtl;                    // global m-tile in [0,24)
                const ushort* wb = Whi + (((size_t)(c * 24 + MT) * 6) * 64 + lane) * 8;
                const ushort* wl = Wlo + (((size_t)(c * 24 + MT) * 6) * 64 + lane) * 8;
                f32x4 acc = {0.f, 0.f, 0.f, 0.f};
#pragma unroll
                for (int ks = 0; ks < 6; ++ks) {
                    short8 whf = *reinterpret_cast<const short8*>(wb + ks * 512);
                    short8 wlf = *reinterpret_cast<const short8*>(wl + ks * 512);
                    acc = __builtin_amdgcn_mfma_f32_16x16x32_bf16(whf, bhi[ks], acc, 0, 0, 0);
                    acc = __builtin_amdgcn_mfma_f32_16x16x32_bf16(wlf, bhi[ks], acc, 0, 0, 0);
                    acc = __builtin_amdgcn_mfma_f32_16x16x32_bf16(whf, blo[ks], acc, 0, 0, 0);
                }
                f32x4 bias4 = *reinterpret_cast<const f32x4*>(
                    Bpk + c * 384 + MT * 16 + quad * 4);
                acc += bias4;
                // D: col=lane&15 -> n16, row=quad*4+reg; ik_local = mtl*4+quad, oc=reg
                *reinterpret_cast<f32x4*>(
                    &kc[((mtl * 4 + quad) * 64 + nt * 16 + n16) * 4]) = acc;
            }
            __syncthreads();

            // ---- phase 2 partial: global ik = p*16 + ikk
#pragma unroll
            for (int ikk = 0; ikk < 16; ++ikk) {
                int ik = p * 16 + ikk;
                int i = ik / 3, kk = ik - i * 3;
                int tt = tglob + kk - 1;
                float xv = (tt >= 0 && tt < 4096) ? cbb[i * 4096 + tt] : 0.f;
                float4 kv = *reinterpret_cast<const float4*>(&kc[(ikk * 64 + n2) * 4]);
                a0 += kv.x * xv; a1 += kv.y * xv; a2 += kv.z * xv; a3 += kv.w * xv;
            }
            __syncthreads();   // kc reused by next pass
        }
        // ---- gate: oc {0,1,2,3} -> o {2c, 32+2c, 2c+1, 32+2c+1}
        {
            float pa = a0 + kbb[(2 * c) * 512 + lg];
            float pb = a1 + kbb[(32 + 2 * c) * 512 + lg];
            float g = (1.f / (1.f + expf(-pa))) * tanhf(pb);
            xxb[(2 * c) * 4096 + tglob] += g;
            pa = a2 + kbb[(2 * c + 1) * 512 + lg];
            pb = a3 + kbb[(32 + 2 * c + 1) * 512 + lg];
            g = (1.f / (1.f + expf(-pa))) * tanhf(pb);
            xxb[(2 * c + 1) * 4096 + tglob] += g;
        }
    }
}

extern "C" void kernel_launch(void* const* d_in, const int* in_sizes, int n_in,
                              void* d_out, int out_size, void* d_ws, size_t ws_size,
                              hipStream_t stream) {
    const float* x      = (const float*)d_in[0];
    const float* c      = (const float*)d_in[1];
    const float* in_w   = (const float*)d_in[2];
    const float* in_b   = (const float*)d_in[3];
    const float* res_ws = (const float*)d_in[4];
    const float* res_bs = (const float*)d_in[5];
    const float* ker_w  = (const float*)d_in[6];
    const float* ker_b  = (const float*)d_in[7];
    const float* bias_w = (const float*)d_in[8];
    const float* bias_b = (const float*)d_in[9];
    const float* ct_w   = (const float*)d_in[10];
    const float* ct_b   = (const float*)d_in[11];
    const float* cb_ws  = (const float*)d_in[12];
    const float* cb_bs  = (const float*)d_in[13];

    float* ws   = (float*)d_ws;
    float* h    = ws;                         // [0, 524288)
    float* kbL  = ws + 524288;                // [524288, 1048576)
    float* tmp  = ws + 1048576;               // [1048576, 1572864)
    float* cb   = ws + 1572864;               // [1572864, 3670016)
    ushort* Whi = (ushort*)(ws + 3670016);    // 1179648 us -> [3670016, 4259840)
    ushort* Wlo = (ushort*)(ws + 4259840);    // 1179648 us -> [4259840, 4849664)
    float* Bpk  = ws + 4849664;               // [4849664, 4855808)
    // high-water 19.42 MB (< 20.97 MB proven by R2's pass)
    float* xx   = (float*)d_out;              // state tensor lives in d_out

    k_pred_in<<<2048, 256, 0, stream>>>(c, in_w, in_b, h);
    for (int j = 0; j < 3; ++j) {
        k_res<<<2048, 256, 0, stream>>>(h,   res_ws + (j * 2 + 0) * 64 * 64 * 3,
                                        res_bs + (j * 2 + 0) * 64, tmp, nullptr);
        k_res<<<2048, 256, 0, stream>>>(tmp, res_ws + (j * 2 + 1) * 64 * 64 * 3,
                                        res_bs + (j * 2 + 1) * 64, h, h);
    }
    k_convt<<<8192, 256, 0, stream>>>(x, ct_w, ct_b, xx);

    const int dils[4] = {1, 3, 9, 27};
    for (int L = 0; L < 4; ++L) {
        k_head<<<2048, 256, 0, stream>>>(h, bias_w, bias_b, kbL, L);
        k_pack_w2<<<576, 256, 0, stream>>>(ker_w, Whi, Wlo, L);
        k_pack_b<<<24, 256, 0, stream>>>(ker_b, Bpk, L);
        k_cblock<<<8192, 256, 0, stream>>>(xx, cb_ws, cb_bs, cb, L, dils[L]);
        k_lvc<<<512, 512, 0, stream>>>(h, cb, kbL, Whi, Wlo, Bpk, xx);
    }
}

// Round 10
// 8806.347 us; speedup vs baseline: 1.1854x; 1.1854x over previous
//
#include <hip/hip_runtime.h>
#include <math.h>

// LVCBlock forward, MI355X (gfx950).
// Shapes: B=16, CIN=32, CCOND=100, Lc=512, HOP=8, T=4096, HID=64, NL=4, K=3, COUT=64.
// ALL inputs and the output are float32.
//
// R10 vs R9 (passed 0.03125 but 2.36ms/k_lvc): R9's __launch_bounds__(512,4)
// capped VGPRs at 64 while holding 48 VGPRs of h-fragments -> scratch spill
// (WRITE_SIZE 2.3GB/dispatch, VALUBusy 1.4%). Fix: h hi/lo fragments live in
// LDS in flat A-fragment order; each wave ds_read_b128's its fragment per
// (ks, hi/lo) per pass (stride-1, conflict-free). VGPR ~50 -> no spill.
// LDS = 24K (Hhi) + 24K (Hlo) + 16K (kc) = 64KB -> 2 blocks/CU.
// Split-precision MFMA math bit-identical to R9 (absmax must stay 0.03125).

#define DEV __device__ __forceinline__

typedef unsigned short ushort;
typedef unsigned int uint;
typedef __attribute__((ext_vector_type(8))) short short8;   // 8 bf16 (4 VGPRs)
typedef __attribute__((ext_vector_type(4))) float f32x4;

DEV float lrelu(float x) { return x > 0.f ? x : 0.2f * x; }

DEV ushort f2bf(float f) {                     // fp32 -> bf16 bits, RNE
    uint u = __float_as_uint(f);
    return (ushort)((u + 0x7fffu + ((u >> 16) & 1u)) >> 16);
}
DEV float bf2f(ushort b) { return __uint_as_float(((uint)b) << 16); }

// ---------------- kernel predictor: input conv (100->64, k=5, pad=2) + lrelu
__global__ void k_pred_in(const float* __restrict__ c, const float* __restrict__ w,
                          const float* __restrict__ bias, float* __restrict__ h) {
    int idx = blockIdx.x * 256 + threadIdx.x;          // 16*64*512
    int l = idx & 511, co = (idx >> 9) & 63, b = idx >> 15;
    float acc = bias[co];
    for (int ci = 0; ci < 100; ++ci) {
        const float* crow = c + (b * 100 + ci) * 512;
        const float* wrow = w + (co * 100 + ci) * 5;
#pragma unroll
        for (int j = 0; j < 5; ++j) {
            int p = l + j - 2;
            if (p >= 0 && p < 512) acc += crow[p] * wrow[j];
        }
    }
    h[idx] = lrelu(acc);
}

// ---------------- residual conv (64->64, k=3, pad=1) + lrelu, optional accumulate
__global__ void k_res(const float* __restrict__ src, const float* __restrict__ w,
                      const float* __restrict__ bias, float* __restrict__ dst,
                      const float* __restrict__ accum) {
    int idx = blockIdx.x * 256 + threadIdx.x;          // 16*64*512
    int l = idx & 511, co = (idx >> 9) & 63, b = idx >> 15;
    float acc = bias[co];
    for (int ci = 0; ci < 64; ++ci) {
        const float* s = src + (b * 64 + ci) * 512;
        const float* wr = w + (co * 64 + ci) * 3;
#pragma unroll
        for (int j = 0; j < 3; ++j) {
            int p = l + j - 1;
            if (p >= 0 && p < 512) acc += s[p] * wr[j];
        }
    }
    float v = lrelu(acc);
    dst[idx] = accum ? accum[idx] + v : v;
}

// ---------------- bias head, ONE layer's 64 channels (k=3, pad=1)
__global__ void k_head(const float* __restrict__ h, const float* __restrict__ w,
                       const float* __restrict__ bias, float* __restrict__ out, int layer) {
    int idx = blockIdx.x * 256 + threadIdx.x;          // 16*64*512
    int l = idx & 511, o = (idx >> 9) & 63, b = idx >> 15;
    int ch = layer * 64 + o;
    float acc = bias[ch];
    for (int ci = 0; ci < 64; ++ci) {
        const float* s = h + (b * 64 + ci) * 512;
        const float* wr = w + (ch * 64 + ci) * 3;
#pragma unroll
        for (int j = 0; j < 3; ++j) {
            int p = l + j - 1;
            if (p >= 0 && p < 512) acc += s[p] * wr[j];
        }
    }
    out[idx] = acc;   // (b*64+o)*512 + l
}

// ---------------- convt_pre: lrelu then ConvTranspose1d(32->32, k=16, s=8, p=4)
__global__ void k_convt(const float* __restrict__ x, const float* __restrict__ w,
                        const float* __restrict__ bias, float* __restrict__ xx) {
    int idx = blockIdx.x * 256 + threadIdx.x;          // 16*32*4096
    int t = idx & 4095, co = (idx >> 12) & 31, b = idx >> 17;
    int m0 = (t + 4) & 7, s0 = (t + 4) >> 3;
    float acc = bias[co];
    for (int ci = 0; ci < 32; ++ci) {
        const float* xr = x + (b * 32 + ci) * 512;
        const float* wr = w + (ci * 32 + co) * 16;
        if (s0 < 512) acc += lrelu(xr[s0]) * wr[m0];
        if (s0 >= 1) acc += lrelu(xr[s0 - 1]) * wr[m0 + 8];
    }
    xx[idx] = acc;
}

// ---------------- dilated conv block: lrelu(conv(lrelu(xx), k=3, dil, pad=dil))
__global__ void k_cblock(const float* __restrict__ xx, const float* __restrict__ w,
                         const float* __restrict__ bias, float* __restrict__ cb,
                         int layer, int dil) {
    int idx = blockIdx.x * 256 + threadIdx.x;          // 16*32*4096
    int t = idx & 4095, ci = (idx >> 12) & 31, b = idx >> 17;
    float acc = bias[layer * 32 + ci];
    for (int c2 = 0; c2 < 32; ++c2) {
        const float* s = xx + (b * 32 + c2) * 4096;
        const float* wr = w + ((layer * 32 + ci) * 32 + c2) * 3;
#pragma unroll
        for (int j = 0; j < 3; ++j) {
            int p = t + (j - 1) * dil;
            if (p >= 0 && p < 4096) acc += lrelu(s[p]) * wr[j];
        }
    }
    cb[idx] = lrelu(acc);
}

// ---------------- weight pack (ONE layer): fp32 -> hi/lo bf16, MFMA A-frag order.
// Flat: (((c*24 + MT)*6 + ks)*64 + lane)*8 + j ; A[m=lane&15][k=quad*8+j].
// Row r = MT*16 + m; ik = r>>2 (=i*3+kk), oc = r&3;
// o = 32*(oc&1) + 2*c + (oc>>1); ch = (i*64+o)*3 + kk.
__global__ void k_pack_w2(const float* __restrict__ ker_w, ushort* __restrict__ Whi,
                          ushort* __restrict__ Wlo, int layer) {
    int g = blockIdx.x * 256 + threadIdx.x;            // < 147456
    int lane = g & 63;
    int g2 = g >> 6;
    int ks = g2 % 6;  int g3 = g2 / 6;
    int mt = g3 % 24; int c = g3 / 24;                 // c in [0,16)
    int m = lane & 15, quad = lane >> 4;
    int r = mt * 16 + m;
    int ik = r >> 2, oc = r & 3;
    int i = ik / 3, kk = ik - i * 3;
    int o = 32 * (oc & 1) + 2 * c + (oc >> 1);
    int ch = (i * 64 + o) * 3 + kk;
    const float* src = ker_w + ((size_t)(layer * 6144 + ch)) * 192 + ks * 32 + quad * 8;
    uint uh[4], ul[4];
#pragma unroll
    for (int t = 0; t < 4; ++t) {
        float f0 = src[2 * t], f1 = src[2 * t + 1];
        ushort h0 = f2bf(f0), h1 = f2bf(f1);
        ushort l0 = f2bf(f0 - bf2f(h0)), l1 = f2bf(f1 - bf2f(h1));
        uh[t] = (uint)h0 | ((uint)h1 << 16);
        ul[t] = (uint)l0 | ((uint)l1 << 16);
    }
    *reinterpret_cast<uint4*>(Whi + (size_t)g * 8) = make_uint4(uh[0], uh[1], uh[2], uh[3]);
    *reinterpret_cast<uint4*>(Wlo + (size_t)g * 8) = make_uint4(ul[0], ul[1], ul[2], ul[3]);
}

// ---------------- bias pack (ONE layer): ker_b -> chunk-row order Bpk[c][r]
__global__ void k_pack_b(const float* __restrict__ ker_b, float* __restrict__ Bpk,
                         int layer) {
    int idx = blockIdx.x * 256 + threadIdx.x;          // < 6144
    int c = idx / 384, r = idx - c * 384;
    int ik = r >> 2, oc = r & 3;
    int i = ik / 3, kk = ik - i * 3;
    int o = 32 * (oc & 1) + 2 * c + (oc >> 1);
    int ch = (i * 64 + o) * 3 + kk;
    Bpk[idx] = ker_b[layer * 6144 + ch];
}

// ---------------- fused: split-precision MFMA kernel-head GEMM + einsum + gate
// Block = (b, 64-l tile, quarter). Chunk c: o in {2c,2c+1,32+2c,32+2c+1}.
// h hi/lo B-fragments prebuilt in LDS in flat A-frag order (per nt):
//   Hfrag[((nt*6+ks)*64+lane)*8+j] = h[n=nt*16+(lane&15)][cj=ks*32+(lane>>4)*8+j]
// Per pass (64 rows = 4 m-tiles x 4 n-tiles): wave w -> nt=w>>1, m-tiles
// (w&1)*2+{0,1}. Per ks: 2 ds_read_b128 (hi,lo) + 4 weight loads + 6 MFMA.
__global__ __launch_bounds__(512) void
k_lvc(const float* __restrict__ h, const float* __restrict__ cb,
      const float* __restrict__ kbL, const ushort* __restrict__ Whi,
      const ushort* __restrict__ Wlo, const float* __restrict__ Bpk,
      float* __restrict__ xx) {
    __shared__ ushort Hhi[12288];       // 24576 B, flat ((nt*6+ks)*64+lane)*8+j
    __shared__ ushort Hlo[12288];       // 24576 B
    __shared__ float kc[4096];          // 16384 B: kc[(ik_local*64+n)*4+oc]
    // total 65536 B -> 2 blocks/CU

    int tid = threadIdx.x;
    int qtr = blockIdx.x & 3;           // fixed quarter per XCD (%8 round-robin)
    int lt = (blockIdx.x >> 2) & 7;
    int b = blockIdx.x >> 5;
    int l0 = lt * 64;

    // ---- build h hi/lo fragments directly from global into LDS
    for (int v = tid; v < 12288; v += 512) {
        int j = v & 7;
        int idx2 = v >> 3;
        int lane_ = idx2 & 63;
        int r2 = idx2 >> 6;
        int ks = r2 % 6, nt_ = r2 / 6;
        int n = nt_ * 16 + (lane_ & 15);
        int cj = ks * 32 + (lane_ >> 4) * 8 + j;
        int ci = cj / 3, jt = cj - ci * 3;
        int p = l0 + n + jt - 1;
        float val = (p >= 0 && p < 512) ? h[(b * 64 + ci) * 512 + p] : 0.f;
        ushort hi = f2bf(val);
        Hhi[v] = hi;
        Hlo[v] = f2bf(val - bf2f(hi));
    }
    __syncthreads();

    int wave = tid >> 6, lane = tid & 63;
    int n16 = lane & 15, quad = lane >> 4;
    int nt = wave >> 1;                 // this wave's n-tile
    int mt0 = (wave & 1) * 2;           // this wave's 2 local m-tiles
    int fbase = (nt * 6) * 64 * 8 + lane * 8;   // fragment base (ks step = 512)

    int h8 = tid & 7, n2 = tid >> 3;    // phase-2 coords
    int tglob = (l0 + n2) * 8 + h8;
    int lg = l0 + n2;
    const float* cbb = cb + b * 32 * 4096;
    const float* kbb = kbL + b * 64 * 512;
    float* xxb = xx + b * 32 * 4096;

    for (int c = qtr * 4; c < qtr * 4 + 4; ++c) {
        float a0 = 0.f, a1 = 0.f, a2 = 0.f, a3 = 0.f;   // phase-2 partials
        for (int p = 0; p < 6; ++p) {
            // ---- phase 1: two m-tile jobs, shared B-fragments per ks
            int MT0 = p * 4 + mt0, MT1 = MT0 + 1;
            const ushort* wb0 = Whi + (((size_t)(c * 24 + MT0) * 6) * 64 + lane) * 8;
            const ushort* wl0 = Wlo + (((size_t)(c * 24 + MT0) * 6) * 64 + lane) * 8;
            const ushort* wb1 = Whi + (((size_t)(c * 24 + MT1) * 6) * 64 + lane) * 8;
            const ushort* wl1 = Wlo + (((size_t)(c * 24 + MT1) * 6) * 64 + lane) * 8;
            f32x4 acc0 = {0.f, 0.f, 0.f, 0.f};
            f32x4 acc1 = {0.f, 0.f, 0.f, 0.f};
#pragma unroll
            for (int ks = 0; ks < 6; ++ks) {
                short8 bhi = *reinterpret_cast<const short8*>(&Hhi[fbase + ks * 512]);
                short8 blo = *reinterpret_cast<const short8*>(&Hlo[fbase + ks * 512]);
                short8 whf0 = *reinterpret_cast<const short8*>(wb0 + ks * 512);
                short8 wlf0 = *reinterpret_cast<const short8*>(wl0 + ks * 512);
                acc0 = __builtin_amdgcn_mfma_f32_16x16x32_bf16(whf0, bhi, acc0, 0, 0, 0);
                acc0 = __builtin_amdgcn_mfma_f32_16x16x32_bf16(wlf0, bhi, acc0, 0, 0, 0);
                acc0 = __builtin_amdgcn_mfma_f32_16x16x32_bf16(whf0, blo, acc0, 0, 0, 0);
                short8 whf1 = *reinterpret_cast<const short8*>(wb1 + ks * 512);
                short8 wlf1 = *reinterpret_cast<const short8*>(wl1 + ks * 512);
                acc1 = __builtin_amdgcn_mfma_f32_16x16x32_bf16(whf1, bhi, acc1, 0, 0, 0);
                acc1 = __builtin_amdgcn_mfma_f32_16x16x32_bf16(wlf1, bhi, acc1, 0, 0, 0);
                acc1 = __builtin_amdgcn_mfma_f32_16x16x32_bf16(whf1, blo, acc1, 0, 0, 0);
            }
            acc0 += *reinterpret_cast<const f32x4*>(Bpk + c * 384 + MT0 * 16 + quad * 4);
            acc1 += *reinterpret_cast<const f32x4*>(Bpk + c * 384 + MT1 * 16 + quad * 4);
            // D: col=lane&15 -> n16, row=quad*4+reg; ik_local = mtl*4+quad, oc=reg
            *reinterpret_cast<f32x4*>(
                &kc[(((mt0 + 0) * 4 + quad) * 64 + nt * 16 + n16) * 4]) = acc0;
            *reinterpret_cast<f32x4*>(
                &kc[(((mt0 + 1) * 4 + quad) * 64 + nt * 16 + n16) * 4]) = acc1;
            __syncthreads();

            // ---- phase 2 partial: global ik = p*16 + ikk
#pragma unroll
            for (int ikk = 0; ikk < 16; ++ikk) {
                int ik = p * 16 + ikk;
                int i = ik / 3, kk = ik - i * 3;
                int tt = tglob + kk - 1;
                float xv = (tt >= 0 && tt < 4096) ? cbb[i * 4096 + tt] : 0.f;
                float4 kv = *reinterpret_cast<const float4*>(&kc[(ikk * 64 + n2) * 4]);
                a0 += kv.x * xv; a1 += kv.y * xv; a2 += kv.z * xv; a3 += kv.w * xv;
            }
            __syncthreads();   // kc reused by next pass
        }
        // ---- gate: oc {0,1,2,3} -> o {2c, 32+2c, 2c+1, 32+2c+1}
        {
            float pa = a0 + kbb[(2 * c) * 512 + lg];
            float pb = a1 + kbb[(32 + 2 * c) * 512 + lg];
            float g = (1.f / (1.f + expf(-pa))) * tanhf(pb);
            xxb[(2 * c) * 4096 + tglob] += g;
            pa = a2 + kbb[(2 * c + 1) * 512 + lg];
            pb = a3 + kbb[(32 + 2 * c + 1) * 512 + lg];
            g = (1.f / (1.f + expf(-pa))) * tanhf(pb);
            xxb[(2 * c + 1) * 4096 + tglob] += g;
        }
    }
}

extern "C" void kernel_launch(void* const* d_in, const int* in_sizes, int n_in,
                              void* d_out, int out_size, void* d_ws, size_t ws_size,
                              hipStream_t stream) {
    const float* x      = (const float*)d_in[0];
    const float* c      = (const float*)d_in[1];
    const float* in_w   = (const float*)d_in[2];
    const float* in_b   = (const float*)d_in[3];
    const float* res_ws = (const float*)d_in[4];
    const float* res_bs = (const float*)d_in[5];
    const float* ker_w  = (const float*)d_in[6];
    const float* ker_b  = (const float*)d_in[7];
    const float* bias_w = (const float*)d_in[8];
    const float* bias_b = (const float*)d_in[9];
    const float* ct_w   = (const float*)d_in[10];
    const float* ct_b   = (const float*)d_in[11];
    const float* cb_ws  = (const float*)d_in[12];
    const float* cb_bs  = (const float*)d_in[13];

    float* ws   = (float*)d_ws;
    float* h    = ws;                         // [0, 524288)
    float* kbL  = ws + 524288;                // [524288, 1048576)
    float* tmp  = ws + 1048576;               // [1048576, 1572864)
    float* cb   = ws + 1572864;               // [1572864, 3670016)
    ushort* Whi = (ushort*)(ws + 3670016);    // [3670016, 4259840)
    ushort* Wlo = (ushort*)(ws + 4259840);    // [4259840, 4849664)
    float* Bpk  = ws + 4849664;               // [4849664, 4855808)
    // high-water 19.42 MB (< 20.97 MB proven by R2's pass)
    float* xx   = (float*)d_out;              // state tensor lives in d_out

    k_pred_in<<<2048, 256, 0, stream>>>(c, in_w, in_b, h);
    for (int j = 0; j < 3; ++j) {
        k_res<<<2048, 256, 0, stream>>>(h,   res_ws + (j * 2 + 0) * 64 * 64 * 3,
                                        res_bs + (j * 2 + 0) * 64, tmp, nullptr);
        k_res<<<2048, 256, 0, stream>>>(tmp, res_ws + (j * 2 + 1) * 64 * 64 * 3,
                                        res_bs + (j * 2 + 1) * 64, h, h);
    }
    k_convt<<<8192, 256, 0, stream>>>(x, ct_w, ct_b, xx);

    const int dils[4] = {1, 3, 9, 27};
    for (int L = 0; L < 4; ++L) {
        k_head<<<2048, 256, 0, stream>>>(h, bias_w, bias_b, kbL, L);
        k_pack_w2<<<576, 256, 0, stream>>>(ker_w, Whi, Wlo, L);
        k_pack_b<<<24, 256, 0, stream>>>(ker_b, Bpk, L);
        k_cblock<<<8192, 256, 0, stream>>>(xx, cb_ws, cb_bs, cb, L, dils[L]);
        k_lvc<<<512, 512, 0, stream>>>(h, cb, kbL, Whi, Wlo, Bpk, xx);
    }
}

// Round 11
// 8286.620 us; speedup vs baseline: 1.2597x; 1.0627x over previous
//
#include <hip/hip_runtime.h>
#include <math.h>

// LVCBlock forward, MI355X (gfx950).
// Shapes: B=16, CIN=32, CCOND=100, Lc=512, HOP=8, T=4096, HID=64, NL=4, K=3, COUT=64.
// ALL inputs and the output are float32.
//
// R11 vs R10 (passed 0.03125, but k_lvc 2.02ms with WRITE_SIZE 1.94GB =
// scratch spill: fully-unrolled ks loop hoisted 36 loads past the 128-VGPR
// cap; spill traffic also thrashed L2 so weights refetched from HBM):
//  (1) weights staged per-pass into LDS (48KB slice, coalesced; source is
//      fragment-flat) -> waves ds_read_b128 fragments; weight L2 traffic
//      drops 4x (no per-n-tile redundant global loads).
//  (2) h hi/lo B-fragments in REGISTERS (48 VGPRs persistent), built once
//      per block from global; LDS = 48K Wstage + 16K kc = 64KB, 2 blocks/CU.
//  (3) sequential m-tile jobs + '#pragma unroll 2' ks loop: transient live
//      set ~12 VGPRs -> total ~95, no spill at the 128 cap.
// Split-precision MFMA math bit-identical to R9/R10 (absmax 0.03125).

#define DEV __device__ __forceinline__

typedef unsigned short ushort;
typedef unsigned int uint;
typedef __attribute__((ext_vector_type(8))) short short8;   // 8 bf16 (4 VGPRs)
typedef __attribute__((ext_vector_type(4))) float f32x4;

DEV float lrelu(float x) { return x > 0.f ? x : 0.2f * x; }

DEV ushort f2bf(float f) {                     // fp32 -> bf16 bits, RNE
    uint u = __float_as_uint(f);
    return (ushort)((u + 0x7fffu + ((u >> 16) & 1u)) >> 16);
}
DEV float bf2f(ushort b) { return __uint_as_float(((uint)b) << 16); }

// ---------------- kernel predictor: input conv (100->64, k=5, pad=2) + lrelu
__global__ void k_pred_in(const float* __restrict__ c, const float* __restrict__ w,
                          const float* __restrict__ bias, float* __restrict__ h) {
    int idx = blockIdx.x * 256 + threadIdx.x;          // 16*64*512
    int l = idx & 511, co = (idx >> 9) & 63, b = idx >> 15;
    float acc = bias[co];
    for (int ci = 0; ci < 100; ++ci) {
        const float* crow = c + (b * 100 + ci) * 512;
        const float* wrow = w + (co * 100 + ci) * 5;
#pragma unroll
        for (int j = 0; j < 5; ++j) {
            int p = l + j - 2;
            if (p >= 0 && p < 512) acc += crow[p] * wrow[j];
        }
    }
    h[idx] = lrelu(acc);
}

// ---------------- residual conv (64->64, k=3, pad=1) + lrelu, optional accumulate
__global__ void k_res(const float* __restrict__ src, const float* __restrict__ w,
                      const float* __restrict__ bias, float* __restrict__ dst,
                      const float* __restrict__ accum) {
    int idx = blockIdx.x * 256 + threadIdx.x;          // 16*64*512
    int l = idx & 511, co = (idx >> 9) & 63, b = idx >> 15;
    float acc = bias[co];
    for (int ci = 0; ci < 64; ++ci) {
        const float* s = src + (b * 64 + ci) * 512;
        const float* wr = w + (co * 64 + ci) * 3;
#pragma unroll
        for (int j = 0; j < 3; ++j) {
            int p = l + j - 1;
            if (p >= 0 && p < 512) acc += s[p] * wr[j];
        }
    }
    float v = lrelu(acc);
    dst[idx] = accum ? accum[idx] + v : v;
}

// ---------------- bias head, ONE layer's 64 channels (k=3, pad=1)
__global__ void k_head(const float* __restrict__ h, const float* __restrict__ w,
                       const float* __restrict__ bias, float* __restrict__ out, int layer) {
    int idx = blockIdx.x * 256 + threadIdx.x;          // 16*64*512
    int l = idx & 511, o = (idx >> 9) & 63, b = idx >> 15;
    int ch = layer * 64 + o;
    float acc = bias[ch];
    for (int ci = 0; ci < 64; ++ci) {
        const float* s = h + (b * 64 + ci) * 512;
        const float* wr = w + (ch * 64 + ci) * 3;
#pragma unroll
        for (int j = 0; j < 3; ++j) {
            int p = l + j - 1;
            if (p >= 0 && p < 512) acc += s[p] * wr[j];
        }
    }
    out[idx] = acc;   // (b*64+o)*512 + l
}

// ---------------- convt_pre: lrelu then ConvTranspose1d(32->32, k=16, s=8, p=4)
__global__ void k_convt(const float* __restrict__ x, const float* __restrict__ w,
                        const float* __restrict__ bias, float* __restrict__ xx) {
    int idx = blockIdx.x * 256 + threadIdx.x;          // 16*32*4096
    int t = idx & 4095, co = (idx >> 12) & 31, b = idx >> 17;
    int m0 = (t + 4) & 7, s0 = (t + 4) >> 3;
    float acc = bias[co];
    for (int ci = 0; ci < 32; ++ci) {
        const float* xr = x + (b * 32 + ci) * 512;
        const float* wr = w + (ci * 32 + co) * 16;
        if (s0 < 512) acc += lrelu(xr[s0]) * wr[m0];
        if (s0 >= 1) acc += lrelu(xr[s0 - 1]) * wr[m0 + 8];
    }
    xx[idx] = acc;
}

// ---------------- dilated conv block: lrelu(conv(lrelu(xx), k=3, dil, pad=dil))
__global__ void k_cblock(const float* __restrict__ xx, const float* __restrict__ w,
                         const float* __restrict__ bias, float* __restrict__ cb,
                         int layer, int dil) {
    int idx = blockIdx.x * 256 + threadIdx.x;          // 16*32*4096
    int t = idx & 4095, ci = (idx >> 12) & 31, b = idx >> 17;
    float acc = bias[layer * 32 + ci];
    for (int c2 = 0; c2 < 32; ++c2) {
        const float* s = xx + (b * 32 + c2) * 4096;
        const float* wr = w + ((layer * 32 + ci) * 32 + c2) * 3;
#pragma unroll
        for (int j = 0; j < 3; ++j) {
            int p = t + (j - 1) * dil;
            if (p >= 0 && p < 4096) acc += lrelu(s[p]) * wr[j];
        }
    }
    cb[idx] = lrelu(acc);
}

// ---------------- weight pack (ONE layer): fp32 -> hi/lo bf16, MFMA A-frag order.
// Flat: (((c*24 + MT)*6 + ks)*64 + lane)*8 + j ; A[m=lane&15][k=quad*8+j].
// Row r = MT*16 + m; ik = r>>2 (=i*3+kk), oc = r&3;
// o = 32*(oc&1) + 2*c + (oc>>1); ch = (i*64+o)*3 + kk.
__global__ void k_pack_w2(const float* __restrict__ ker_w, ushort* __restrict__ Whi,
                          ushort* __restrict__ Wlo, int layer) {
    int g = blockIdx.x * 256 + threadIdx.x;            // < 147456
    int lane = g & 63;
    int g2 = g >> 6;
    int ks = g2 % 6;  int g3 = g2 / 6;
    int mt = g3 % 24; int c = g3 / 24;                 // c in [0,16)
    int m = lane & 15, quad = lane >> 4;
    int r = mt * 16 + m;
    int ik = r >> 2, oc = r & 3;
    int i = ik / 3, kk = ik - i * 3;
    int o = 32 * (oc & 1) + 2 * c + (oc >> 1);
    int ch = (i * 64 + o) * 3 + kk;
    const float* src = ker_w + ((size_t)(layer * 6144 + ch)) * 192 + ks * 32 + quad * 8;
    uint uh[4], ul[4];
#pragma unroll
    for (int t = 0; t < 4; ++t) {
        float f0 = src[2 * t], f1 = src[2 * t + 1];
        ushort h0 = f2bf(f0), h1 = f2bf(f1);
        ushort l0 = f2bf(f0 - bf2f(h0)), l1 = f2bf(f1 - bf2f(h1));
        uh[t] = (uint)h0 | ((uint)h1 << 16);
        ul[t] = (uint)l0 | ((uint)l1 << 16);
    }
    *reinterpret_cast<uint4*>(Whi + (size_t)g * 8) = make_uint4(uh[0], uh[1], uh[2], uh[3]);
    *reinterpret_cast<uint4*>(Wlo + (size_t)g * 8) = make_uint4(ul[0], ul[1], ul[2], ul[3]);
}

// ---------------- bias pack (ONE layer): ker_b -> chunk-row order Bpk[c][r]
__global__ void k_pack_b(const float* __restrict__ ker_b, float* __restrict__ Bpk,
                         int layer) {
    int idx = blockIdx.x * 256 + threadIdx.x;          // < 6144
    int c = idx / 384, r = idx - c * 384;
    int ik = r >> 2, oc = r & 3;
    int i = ik / 3, kk = ik - i * 3;
    int o = 32 * (oc & 1) + 2 * c + (oc >> 1);
    int ch = (i * 64 + o) * 3 + kk;
    Bpk[idx] = ker_b[layer * 6144 + ch];
}

// ---------------- fused: split-precision MFMA kernel-head GEMM + einsum + gate
// Block = (b, 64-l tile, quarter). Chunk c: o in {2c,2c+1,32+2c,32+2c+1}.
// Per pass (64 rows = 4 m-tiles x 4 n-tiles): weights staged to LDS (48KB,
// coalesced; source already fragment-flat), wave w -> nt=w>>1 (B-frags in
// registers), m-tiles (w&1)*2+{0,1} SEQUENTIAL. 3 barriers/pass.
__global__ __launch_bounds__(512) void
k_lvc(const float* __restrict__ h, const float* __restrict__ cb,
      const float* __restrict__ kbL, const ushort* __restrict__ Whi,
      const ushort* __restrict__ Wlo, const float* __restrict__ Bpk,
      float* __restrict__ xx) {
    __shared__ ushort WstHi[12288];     // 24576 B: pass slice ((mtl*6+ks)*64+lane)*8+j
    __shared__ ushort WstLo[12288];     // 24576 B
    __shared__ float kc[4096];          // 16384 B: kc[(ik_local*64+n)*4+oc]
    // total 65536 B -> 2 blocks/CU

    int tid = threadIdx.x;
    int qtr = blockIdx.x & 3;           // fixed quarter per XCD (%8 round-robin)
    int lt = (blockIdx.x >> 2) & 7;
    int b = blockIdx.x >> 5;
    int l0 = lt * 64;

    int wave = tid >> 6, lane = tid & 63;
    int n16 = lane & 15, quad = lane >> 4;
    int nt = wave >> 1;                 // this wave's n-tile
    int mt0 = (wave & 1) * 2;           // this wave's 2 local m-tiles

    // ---- build h hi/lo B-fragments in registers (48 VGPRs), from global
    short8 bhi[6], blo[6];
    {
        int n = nt * 16 + n16;
        for (int ks = 0; ks < 6; ++ks) {
            short8 vh, vl;
#pragma unroll
            for (int j = 0; j < 8; ++j) {
                int cj = ks * 32 + quad * 8 + j;
                int ci = cj / 3, jt = cj - ci * 3;
                int p = l0 + n + jt - 1;
                float val = (p >= 0 && p < 512) ? h[(b * 64 + ci) * 512 + p] : 0.f;
                ushort hi = f2bf(val);
                vh[j] = (short)hi;
                vl[j] = (short)f2bf(val - bf2f(hi));
            }
            bhi[ks] = vh;
            blo[ks] = vl;
        }
    }

    int h8 = tid & 7, n2 = tid >> 3;    // phase-2 coords
    int tglob = (l0 + n2) * 8 + h8;
    int lg = l0 + n2;
    const float* cbb = cb + b * 32 * 4096;
    const float* kbb = kbL + b * 64 * 512;
    float* xxb = xx + b * 32 * 4096;

    for (int c = qtr * 4; c < qtr * 4 + 4; ++c) {
        float a0 = 0.f, a1 = 0.f, a2 = 0.f, a3 = 0.f;   // phase-2 partials
        for (int p = 0; p < 6; ++p) {
            // ---- stage this pass's weight slice into LDS (coalesced uint4)
            {
                const uint4* srcH = reinterpret_cast<const uint4*>(
                    Whi + ((size_t)(c * 24 + p * 4) * 6) * 512);
                const uint4* srcL = reinterpret_cast<const uint4*>(
                    Wlo + ((size_t)(c * 24 + p * 4) * 6) * 512);
                uint4* dH = reinterpret_cast<uint4*>(WstHi);
                uint4* dL = reinterpret_cast<uint4*>(WstLo);
                for (int v = tid; v < 1536; v += 512) {
                    dH[v] = srcH[v];
                    dL[v] = srcL[v];
                }
            }
            __syncthreads();

            // ---- phase 1: two m-tile jobs, sequential (low register pressure)
            for (int jj = 0; jj < 2; ++jj) {
                int mtl = mt0 + jj;
                int MT = p * 4 + mtl;
                const ushort* wh = WstHi + (mtl * 6) * 512 + lane * 8;
                const ushort* wl = WstLo + (mtl * 6) * 512 + lane * 8;
                f32x4 acc = {0.f, 0.f, 0.f, 0.f};
#pragma unroll 2
                for (int ks = 0; ks < 6; ++ks) {
                    short8 whf = *reinterpret_cast<const short8*>(wh + ks * 512);
                    short8 wlf = *reinterpret_cast<const short8*>(wl + ks * 512);
                    acc = __builtin_amdgcn_mfma_f32_16x16x32_bf16(whf, bhi[ks], acc, 0, 0, 0);
                    acc = __builtin_amdgcn_mfma_f32_16x16x32_bf16(wlf, bhi[ks], acc, 0, 0, 0);
                    acc = __builtin_amdgcn_mfma_f32_16x16x32_bf16(whf, blo[ks], acc, 0, 0, 0);
                }
                acc += *reinterpret_cast<const f32x4*>(Bpk + c * 384 + MT * 16 + quad * 4);
                // D: col=lane&15 -> n16, row=quad*4+reg; ik_local = mtl*4+quad, oc=reg
                *reinterpret_cast<f32x4*>(
                    &kc[((mtl * 4 + quad) * 64 + nt * 16 + n16) * 4]) = acc;
            }
            __syncthreads();

            // ---- phase 2 partial: global ik = p*16 + ikk
#pragma unroll
            for (int ikk = 0; ikk < 16; ++ikk) {
                int ik = p * 16 + ikk;
                int i = ik / 3, kk = ik - i * 3;
                int tt = tglob + kk - 1;
                float xv = (tt >= 0 && tt < 4096) ? cbb[i * 4096 + tt] : 0.f;
                float4 kv = *reinterpret_cast<const float4*>(&kc[(ikk * 64 + n2) * 4]);
                a0 += kv.x * xv; a1 += kv.y * xv; a2 += kv.z * xv; a3 += kv.w * xv;
            }
            __syncthreads();   // Wst/kc reused by next pass
        }
        // ---- gate: oc {0,1,2,3} -> o {2c, 32+2c, 2c+1, 32+2c+1}
        {
            float pa = a0 + kbb[(2 * c) * 512 + lg];
            float pb = a1 + kbb[(32 + 2 * c) * 512 + lg];
            float g = (1.f / (1.f + expf(-pa))) * tanhf(pb);
            xxb[(2 * c) * 4096 + tglob] += g;
            pa = a2 + kbb[(2 * c + 1) * 512 + lg];
            pb = a3 + kbb[(32 + 2 * c + 1) * 512 + lg];
            g = (1.f / (1.f + expf(-pa))) * tanhf(pb);
            xxb[(2 * c + 1) * 4096 + tglob] += g;
        }
    }
}

extern "C" void kernel_launch(void* const* d_in, const int* in_sizes, int n_in,
                              void* d_out, int out_size, void* d_ws, size_t ws_size,
                              hipStream_t stream) {
    const float* x      = (const float*)d_in[0];
    const float* c      = (const float*)d_in[1];
    const float* in_w   = (const float*)d_in[2];
    const float* in_b   = (const float*)d_in[3];
    const float* res_ws = (const float*)d_in[4];
    const float* res_bs = (const float*)d_in[5];
    const float* ker_w  = (const float*)d_in[6];
    const float* ker_b  = (const float*)d_in[7];
    const float* bias_w = (const float*)d_in[8];
    const float* bias_b = (const float*)d_in[9];
    const float* ct_w   = (const float*)d_in[10];
    const float* ct_b   = (const float*)d_in[11];
    const float* cb_ws  = (const float*)d_in[12];
    const float* cb_bs  = (const float*)d_in[13];

    float* ws   = (float*)d_ws;
    float* h    = ws;                         // [0, 524288)
    float* kbL  = ws + 524288;                // [524288, 1048576)
    float* tmp  = ws + 1048576;               // [1048576, 1572864)
    float* cb   = ws + 1572864;               // [1572864, 3670016)
    ushort* Whi = (ushort*)(ws + 3670016);    // [3670016, 4259840)
    ushort* Wlo = (ushort*)(ws + 4259840);    // [4259840, 4849664)
    float* Bpk  = ws + 4849664;               // [4849664, 4855808)
    // high-water 19.42 MB (< 20.97 MB proven by R2's pass)
    float* xx   = (float*)d_out;              // state tensor lives in d_out

    k_pred_in<<<2048, 256, 0, stream>>>(c, in_w, in_b, h);
    for (int j = 0; j < 3; ++j) {
        k_res<<<2048, 256, 0, stream>>>(h,   res_ws + (j * 2 + 0) * 64 * 64 * 3,
                                        res_bs + (j * 2 + 0) * 64, tmp, nullptr);
        k_res<<<2048, 256, 0, stream>>>(tmp, res_ws + (j * 2 + 1) * 64 * 64 * 3,
                                        res_bs + (j * 2 + 1) * 64, h, h);
    }
    k_convt<<<8192, 256, 0, stream>>>(x, ct_w, ct_b, xx);

    const int dils[4] = {1, 3, 9, 27};
    for (int L = 0; L < 4; ++L) {
        k_head<<<2048, 256, 0, stream>>>(h, bias_w, bias_b, kbL, L);
        k_pack_w2<<<576, 256, 0, stream>>>(ker_w, Whi, Wlo, L);
        k_pack_b<<<24, 256, 0, stream>>>(ker_b, Bpk, L);
        k_cblock<<<8192, 256, 0, stream>>>(xx, cb_ws, cb_bs, cb, L, dils[L]);
        k_lvc<<<512, 512, 0, stream>>>(h, cb, kbL, Whi, Wlo, Bpk, xx);
    }
}

// Round 12
// 7142.857 us; speedup vs baseline: 1.4615x; 1.1601x over previous
//
#include <hip/hip_runtime.h>
#include <math.h>

// LVCBlock forward, MI355X (gfx950).
// Shapes: B=16, CIN=32, CCOND=100, Lc=512, HOP=8, T=4096, HID=64, NL=4, K=3, COUT=64.
// ALL inputs and the output are float32.
//
// R12: split-precision MFMA (math bit-identical to R9-R11, absmax 0.03125),
// avoiding all three catalogued MFMA codegen failures:
//   R9: launch_bounds min-waves clause -> VGPR cap 64 -> spill.
//   R10: full unroll + 36 hoisted GLOBAL loads > 128 cap -> spill.
//   R11: partial unroll -> dynamic register-array indexing -> VALU storm
//        (VALUBusy 83%, 25x instruction bloat); also 64KB LDS -> 1 block/CU.
// Design: l-tile 32, 256-thr blocks, grid 1024 (b x 16 lt x 4 qtr);
// __launch_bounds__(256,2) -> VGPR cap 256 (no spill); ks loop FULLY
// unrolled (static indices only); weights staged per-pass to LDS (48KB),
// H hi/lo fragments persistent in registers (48 VGPRs, safe under 256);
// LDS = 48K Wst + 8K kc = 56KB < 61440 -> 2 blocks/CU (R8-verified bound).

#define DEV __device__ __forceinline__

typedef unsigned short ushort;
typedef unsigned int uint;
typedef __attribute__((ext_vector_type(8))) short short8;   // 8 bf16 (4 VGPRs)
typedef __attribute__((ext_vector_type(4))) float f32x4;

DEV float lrelu(float x) { return x > 0.f ? x : 0.2f * x; }

DEV ushort f2bf(float f) {                     // fp32 -> bf16 bits, RNE
    uint u = __float_as_uint(f);
    return (ushort)((u + 0x7fffu + ((u >> 16) & 1u)) >> 16);
}
DEV float bf2f(ushort b) { return __uint_as_float(((uint)b) << 16); }

// ---------------- kernel predictor: input conv (100->64, k=5, pad=2) + lrelu
__global__ void k_pred_in(const float* __restrict__ c, const float* __restrict__ w,
                          const float* __restrict__ bias, float* __restrict__ h) {
    int idx = blockIdx.x * 256 + threadIdx.x;          // 16*64*512
    int l = idx & 511, co = (idx >> 9) & 63, b = idx >> 15;
    float acc = bias[co];
    for (int ci = 0; ci < 100; ++ci) {
        const float* crow = c + (b * 100 + ci) * 512;
        const float* wrow = w + (co * 100 + ci) * 5;
#pragma unroll
        for (int j = 0; j < 5; ++j) {
            int p = l + j - 2;
            if (p >= 0 && p < 512) acc += crow[p] * wrow[j];
        }
    }
    h[idx] = lrelu(acc);
}

// ---------------- residual conv (64->64, k=3, pad=1) + lrelu, optional accumulate
__global__ void k_res(const float* __restrict__ src, const float* __restrict__ w,
                      const float* __restrict__ bias, float* __restrict__ dst,
                      const float* __restrict__ accum) {
    int idx = blockIdx.x * 256 + threadIdx.x;          // 16*64*512
    int l = idx & 511, co = (idx >> 9) & 63, b = idx >> 15;
    float acc = bias[co];
    for (int ci = 0; ci < 64; ++ci) {
        const float* s = src + (b * 64 + ci) * 512;
        const float* wr = w + (co * 64 + ci) * 3;
#pragma unroll
        for (int j = 0; j < 3; ++j) {
            int p = l + j - 1;
            if (p >= 0 && p < 512) acc += s[p] * wr[j];
        }
    }
    float v = lrelu(acc);
    dst[idx] = accum ? accum[idx] + v : v;
}

// ---------------- bias head, ONE layer's 64 channels (k=3, pad=1)
__global__ void k_head(const float* __restrict__ h, const float* __restrict__ w,
                       const float* __restrict__ bias, float* __restrict__ out, int layer) {
    int idx = blockIdx.x * 256 + threadIdx.x;          // 16*64*512
    int l = idx & 511, o = (idx >> 9) & 63, b = idx >> 15;
    int ch = layer * 64 + o;
    float acc = bias[ch];
    for (int ci = 0; ci < 64; ++ci) {
        const float* s = h + (b * 64 + ci) * 512;
        const float* wr = w + (ch * 64 + ci) * 3;
#pragma unroll
        for (int j = 0; j < 3; ++j) {
            int p = l + j - 1;
            if (p >= 0 && p < 512) acc += s[p] * wr[j];
        }
    }
    out[idx] = acc;   // (b*64+o)*512 + l
}

// ---------------- convt_pre: lrelu then ConvTranspose1d(32->32, k=16, s=8, p=4)
__global__ void k_convt(const float* __restrict__ x, const float* __restrict__ w,
                        const float* __restrict__ bias, float* __restrict__ xx) {
    int idx = blockIdx.x * 256 + threadIdx.x;          // 16*32*4096
    int t = idx & 4095, co = (idx >> 12) & 31, b = idx >> 17;
    int m0 = (t + 4) & 7, s0 = (t + 4) >> 3;
    float acc = bias[co];
    for (int ci = 0; ci < 32; ++ci) {
        const float* xr = x + (b * 32 + ci) * 512;
        const float* wr = w + (ci * 32 + co) * 16;
        if (s0 < 512) acc += lrelu(xr[s0]) * wr[m0];
        if (s0 >= 1) acc += lrelu(xr[s0 - 1]) * wr[m0 + 8];
    }
    xx[idx] = acc;
}

// ---------------- dilated conv block: lrelu(conv(lrelu(xx), k=3, dil, pad=dil))
__global__ void k_cblock(const float* __restrict__ xx, const float* __restrict__ w,
                         const float* __restrict__ bias, float* __restrict__ cb,
                         int layer, int dil) {
    int idx = blockIdx.x * 256 + threadIdx.x;          // 16*32*4096
    int t = idx & 4095, ci = (idx >> 12) & 31, b = idx >> 17;
    float acc = bias[layer * 32 + ci];
    for (int c2 = 0; c2 < 32; ++c2) {
        const float* s = xx + (b * 32 + c2) * 4096;
        const float* wr = w + ((layer * 32 + ci) * 32 + c2) * 3;
#pragma unroll
        for (int j = 0; j < 3; ++j) {
            int p = t + (j - 1) * dil;
            if (p >= 0 && p < 4096) acc += lrelu(s[p]) * wr[j];
        }
    }
    cb[idx] = lrelu(acc);
}

// ---------------- weight pack (ONE layer): fp32 -> hi/lo bf16, MFMA A-frag order.
// Flat: (((c*24 + MT)*6 + ks)*64 + lane)*8 + j ; A[m=lane&15][k=quad*8+j].
// Row r = MT*16 + m; ik = r>>2 (=i*3+kk), oc = r&3;
// o = 32*(oc&1) + 2*c + (oc>>1); ch = (i*64+o)*3 + kk.
__global__ void k_pack_w2(const float* __restrict__ ker_w, ushort* __restrict__ Whi,
                          ushort* __restrict__ Wlo, int layer) {
    int g = blockIdx.x * 256 + threadIdx.x;            // < 147456
    int lane = g & 63;
    int g2 = g >> 6;
    int ks = g2 % 6;  int g3 = g2 / 6;
    int mt = g3 % 24; int c = g3 / 24;                 // c in [0,16)
    int m = lane & 15, quad = lane >> 4;
    int r = mt * 16 + m;
    int ik = r >> 2, oc = r & 3;
    int i = ik / 3, kk = ik - i * 3;
    int o = 32 * (oc & 1) + 2 * c + (oc >> 1);
    int ch = (i * 64 + o) * 3 + kk;
    const float* src = ker_w + ((size_t)(layer * 6144 + ch)) * 192 + ks * 32 + quad * 8;
    uint uh[4], ul[4];
#pragma unroll
    for (int t = 0; t < 4; ++t) {
        float f0 = src[2 * t], f1 = src[2 * t + 1];
        ushort h0 = f2bf(f0), h1 = f2bf(f1);
        ushort l0 = f2bf(f0 - bf2f(h0)), l1 = f2bf(f1 - bf2f(h1));
        uh[t] = (uint)h0 | ((uint)h1 << 16);
        ul[t] = (uint)l0 | ((uint)l1 << 16);
    }
    *reinterpret_cast<uint4*>(Whi + (size_t)g * 8) = make_uint4(uh[0], uh[1], uh[2], uh[3]);
    *reinterpret_cast<uint4*>(Wlo + (size_t)g * 8) = make_uint4(ul[0], ul[1], ul[2], ul[3]);
}

// ---------------- bias pack (ONE layer): ker_b -> chunk-row order Bpk[c][r]
__global__ void k_pack_b(const float* __restrict__ ker_b, float* __restrict__ Bpk,
                         int layer) {
    int idx = blockIdx.x * 256 + threadIdx.x;          // < 6144
    int c = idx / 384, r = idx - c * 384;
    int ik = r >> 2, oc = r & 3;
    int i = ik / 3, kk = ik - i * 3;
    int o = 32 * (oc & 1) + 2 * c + (oc >> 1);
    int ch = (i * 64 + o) * 3 + kk;
    Bpk[idx] = ker_b[layer * 6144 + ch];
}

// ---------------- fused: split-precision MFMA kernel-head GEMM + einsum + gate
// Block = (b, 32-l tile, quarter), 256 threads (4 waves). Chunk c: o in
// {2c,2c+1,32+2c,32+2c+1}. Pass = 4 m-tiles x 2 n-tiles; wave w -> nt=w&1,
// m-tiles (w>>1)*2+{0,1}. Weights staged per-pass to LDS (source already
// fragment-flat); H hi/lo fragments persistent in registers (one nt/wave).
__global__ __launch_bounds__(256, 2) void
k_lvc(const float* __restrict__ h, const float* __restrict__ cb,
      const float* __restrict__ kbL, const ushort* __restrict__ Whi,
      const ushort* __restrict__ Wlo, const float* __restrict__ Bpk,
      float* __restrict__ xx) {
    __shared__ ushort WstHi[12288];     // 24576 B: ((mtl*6+ks)*64+lane)*8+j
    __shared__ ushort WstLo[12288];     // 24576 B
    __shared__ float kc[2048];          // 8192 B: kc[(ik_local*32+n)*4+oc]
    // total 57344 B -> 2 blocks/CU (R8-verified: 61440 co-schedules)

    int tid = threadIdx.x;
    int qtr = blockIdx.x & 3;           // fixed quarter per XCD (%8 round-robin)
    int lt = (blockIdx.x >> 2) & 15;
    int b = blockIdx.x >> 6;
    int l0 = lt * 32;

    int wave = tid >> 6, lane = tid & 63;
    int n16 = lane & 15, quad = lane >> 4;
    int nt = wave & 1;                  // this wave's n-tile (of 2)
    int mt0 = (wave >> 1) * 2;          // this wave's 2 local m-tiles

    // ---- build h hi/lo B-fragments in registers (48 VGPRs), from global.
    // B[k=quad*8+j][n=nt*16+n16]; cj = k index into the (cjc,jt) h window.
    short8 bhi[6], blo[6];
    {
        int n = nt * 16 + n16;
#pragma unroll
        for (int ks = 0; ks < 6; ++ks) {
            short8 vh, vl;
#pragma unroll
            for (int j = 0; j < 8; ++j) {
                int cj = ks * 32 + quad * 8 + j;
                int ci = cj / 3, jt = cj - ci * 3;
                int p = l0 + n + jt - 1;
                float val = (p >= 0 && p < 512) ? h[(b * 64 + ci) * 512 + p] : 0.f;
                ushort hi = f2bf(val);
                vh[j] = (short)hi;
                vl[j] = (short)f2bf(val - bf2f(hi));
            }
            bhi[ks] = vh;
            blo[ks] = vl;
        }
    }

    int h8 = tid & 7, n2 = tid >> 3;    // phase-2: hop h8, location n2 in [0,32)
    int lg = l0 + n2;
    int tglob = lg * 8 + h8;
    const float* cbb = cb + b * 32 * 4096;
    const float* kbb = kbL + b * 64 * 512;
    float* xxb = xx + b * 32 * 4096;

    for (int cc = 0; cc < 4; ++cc) {
        int c = qtr * 4 + cc;
        float a0 = 0.f, a1 = 0.f, a2 = 0.f, a3 = 0.f;   // phase-2 partials
        for (int p = 0; p < 6; ++p) {
            // ---- stage this pass's weight slice into LDS (coalesced uint4)
            {
                const uint4* srcH = reinterpret_cast<const uint4*>(
                    Whi + ((size_t)(c * 24 + p * 4) * 6) * 512);
                const uint4* srcL = reinterpret_cast<const uint4*>(
                    Wlo + ((size_t)(c * 24 + p * 4) * 6) * 512);
                uint4* dH = reinterpret_cast<uint4*>(WstHi);
                uint4* dL = reinterpret_cast<uint4*>(WstLo);
#pragma unroll
                for (int v = 0; v < 6; ++v) {
                    dH[tid + v * 256] = srcH[tid + v * 256];
                    dL[tid + v * 256] = srcL[tid + v * 256];
                }
            }
            __syncthreads();

            // ---- phase 1: two m-tile jobs, sequential; ks fully unrolled
#pragma unroll
            for (int jj = 0; jj < 2; ++jj) {
                int mtl = mt0 + jj;
                int MT = p * 4 + mtl;
                const ushort* wh = WstHi + (mtl * 6) * 512 + lane * 8;
                const ushort* wl = WstLo + (mtl * 6) * 512 + lane * 8;
                f32x4 acc = {0.f, 0.f, 0.f, 0.f};
#pragma unroll
                for (int ks = 0; ks < 6; ++ks) {
                    short8 whf = *reinterpret_cast<const short8*>(wh + ks * 512);
                    short8 wlf = *reinterpret_cast<const short8*>(wl + ks * 512);
                    acc = __builtin_amdgcn_mfma_f32_16x16x32_bf16(whf, bhi[ks], acc, 0, 0, 0);
                    acc = __builtin_amdgcn_mfma_f32_16x16x32_bf16(wlf, bhi[ks], acc, 0, 0, 0);
                    acc = __builtin_amdgcn_mfma_f32_16x16x32_bf16(whf, blo[ks], acc, 0, 0, 0);
                }
                acc += *reinterpret_cast<const f32x4*>(Bpk + c * 384 + MT * 16 + quad * 4);
                // D: col=lane&15 -> n16, row=quad*4+reg; ik_local = mtl*4+quad, oc=reg
                *reinterpret_cast<f32x4*>(
                    &kc[((mtl * 4 + quad) * 32 + nt * 16 + n16) * 4]) = acc;
            }
            __syncthreads();

            // ---- phase 2 partial: global ik = p*16 + ikk
#pragma unroll
            for (int ikk = 0; ikk < 16; ++ikk) {
                int ik = p * 16 + ikk;
                int i = ik / 3, kk = ik - i * 3;
                int tt = tglob + kk - 1;
                float xv = (tt >= 0 && tt < 4096) ? cbb[i * 4096 + tt] : 0.f;
                float4 kv = *reinterpret_cast<const float4*>(&kc[(ikk * 32 + n2) * 4]);
                a0 += kv.x * xv; a1 += kv.y * xv; a2 += kv.z * xv; a3 += kv.w * xv;
            }
            __syncthreads();   // Wst/kc reused by next pass
        }
        // ---- gate: oc {0,1,2,3} -> o {2c, 32+2c, 2c+1, 32+2c+1}
        {
            float pa = a0 + kbb[(2 * c) * 512 + lg];
            float pb = a1 + kbb[(32 + 2 * c) * 512 + lg];
            float g = (1.f / (1.f + expf(-pa))) * tanhf(pb);
            xxb[(2 * c) * 4096 + tglob] += g;
            pa = a2 + kbb[(2 * c + 1) * 512 + lg];
            pb = a3 + kbb[(32 + 2 * c + 1) * 512 + lg];
            g = (1.f / (1.f + expf(-pa))) * tanhf(pb);
            xxb[(2 * c + 1) * 4096 + tglob] += g;
        }
    }
}

extern "C" void kernel_launch(void* const* d_in, const int* in_sizes, int n_in,
                              void* d_out, int out_size, void* d_ws, size_t ws_size,
                              hipStream_t stream) {
    const float* x      = (const float*)d_in[0];
    const float* c      = (const float*)d_in[1];
    const float* in_w   = (const float*)d_in[2];
    const float* in_b   = (const float*)d_in[3];
    const float* res_ws = (const float*)d_in[4];
    const float* res_bs = (const float*)d_in[5];
    const float* ker_w  = (const float*)d_in[6];
    const float* ker_b  = (const float*)d_in[7];
    const float* bias_w = (const float*)d_in[8];
    const float* bias_b = (const float*)d_in[9];
    const float* ct_w   = (const float*)d_in[10];
    const float* ct_b   = (const float*)d_in[11];
    const float* cb_ws  = (const float*)d_in[12];
    const float* cb_bs  = (const float*)d_in[13];

    float* ws   = (float*)d_ws;
    float* h    = ws;                         // [0, 524288)
    float* kbL  = ws + 524288;                // [524288, 1048576)
    float* tmp  = ws + 1048576;               // [1048576, 1572864)
    float* cb   = ws + 1572864;               // [1572864, 3670016)
    ushort* Whi = (ushort*)(ws + 3670016);    // [3670016, 4259840)
    ushort* Wlo = (ushort*)(ws + 4259840);    // [4259840, 4849664)
    float* Bpk  = ws + 4849664;               // [4849664, 4855808)
    // high-water 19.42 MB (< 20.97 MB proven by R2's pass)
    float* xx   = (float*)d_out;              // state tensor lives in d_out

    k_pred_in<<<2048, 256, 0, stream>>>(c, in_w, in_b, h);
    for (int j = 0; j < 3; ++j) {
        k_res<<<2048, 256, 0, stream>>>(h,   res_ws + (j * 2 + 0) * 64 * 64 * 3,
                                        res_bs + (j * 2 + 0) * 64, tmp, nullptr);
        k_res<<<2048, 256, 0, stream>>>(tmp, res_ws + (j * 2 + 1) * 64 * 64 * 3,
                                        res_bs + (j * 2 + 1) * 64, h, h);
    }
    k_convt<<<8192, 256, 0, stream>>>(x, ct_w, ct_b, xx);

    const int dils[4] = {1, 3, 9, 27};
    for (int L = 0; L < 4; ++L) {
        k_head<<<2048, 256, 0, stream>>>(h, bias_w, bias_b, kbL, L);
        k_pack_w2<<<576, 256, 0, stream>>>(ker_w, Whi, Wlo, L);
        k_pack_b<<<24, 256, 0, stream>>>(ker_b, Bpk, L);
        k_cblock<<<8192, 256, 0, stream>>>(xx, cb_ws, cb_bs, cb, L, dils[L]);
        k_lvc<<<1024, 256, 0, stream>>>(h, cb, kbL, Whi, Wlo, Bpk, xx);
    }
}

// Round 13
// 1864.904 us; speedup vs baseline: 5.5976x; 3.8301x over previous
//
#include <hip/hip_runtime.h>
#include <math.h>

// LVCBlock forward, MI355X (gfx950).
// Shapes: B=16, CIN=32, CCOND=100, Lc=512, HOP=8, T=4096, HID=64, NL=4, K=3, COUT=64.
// ALL inputs and the output are float32.
//
// R13: split-precision MFMA (math bit-identical to R9-R12, absmax 0.03125).
// Failure catalog: R9 spill (VGPR cap 64), R10 spill (hoisted global loads),
// R11 VALU storm (partial unroll over register arrays), R12 spill (48
// persistent fragment VGPRs + hoisted LDS loads > 128).
// Fix: NO register-resident fragments. Both MFMA operands in LDS, fetched by
// ds_read_b128 at use; '#pragma unroll 2' is safe (ks feeds addresses only).
// Pass = 2 m-tiles x 2 n-tiles (one MFMA job per wave). LDS: Hfrag 24K +
// Wst 24K + kc 4K = 52KB -> 2 blocks/CU. Persistent VGPR ~25, total ~70.

#define DEV __device__ __forceinline__

typedef unsigned short ushort;
typedef unsigned int uint;
typedef __attribute__((ext_vector_type(8))) short short8;   // 8 bf16 (4 VGPRs)
typedef __attribute__((ext_vector_type(4))) float f32x4;

DEV float lrelu(float x) { return x > 0.f ? x : 0.2f * x; }

DEV ushort f2bf(float f) {                     // fp32 -> bf16 bits, RNE
    uint u = __float_as_uint(f);
    return (ushort)((u + 0x7fffu + ((u >> 16) & 1u)) >> 16);
}
DEV float bf2f(ushort b) { return __uint_as_float(((uint)b) << 16); }

// ---------------- kernel predictor: input conv (100->64, k=5, pad=2) + lrelu
__global__ void k_pred_in(const float* __restrict__ c, const float* __restrict__ w,
                          const float* __restrict__ bias, float* __restrict__ h) {
    int idx = blockIdx.x * 256 + threadIdx.x;          // 16*64*512
    int l = idx & 511, co = (idx >> 9) & 63, b = idx >> 15;
    float acc = bias[co];
    for (int ci = 0; ci < 100; ++ci) {
        const float* crow = c + (b * 100 + ci) * 512;
        const float* wrow = w + (co * 100 + ci) * 5;
#pragma unroll
        for (int j = 0; j < 5; ++j) {
            int p = l + j - 2;
            if (p >= 0 && p < 512) acc += crow[p] * wrow[j];
        }
    }
    h[idx] = lrelu(acc);
}

// ---------------- residual conv (64->64, k=3, pad=1) + lrelu, optional accumulate
__global__ void k_res(const float* __restrict__ src, const float* __restrict__ w,
                      const float* __restrict__ bias, float* __restrict__ dst,
                      const float* __restrict__ accum) {
    int idx = blockIdx.x * 256 + threadIdx.x;          // 16*64*512
    int l = idx & 511, co = (idx >> 9) & 63, b = idx >> 15;
    float acc = bias[co];
    for (int ci = 0; ci < 64; ++ci) {
        const float* s = src + (b * 64 + ci) * 512;
        const float* wr = w + (co * 64 + ci) * 3;
#pragma unroll
        for (int j = 0; j < 3; ++j) {
            int p = l + j - 1;
            if (p >= 0 && p < 512) acc += s[p] * wr[j];
        }
    }
    float v = lrelu(acc);
    dst[idx] = accum ? accum[idx] + v : v;
}

// ---------------- bias head, ONE layer's 64 channels (k=3, pad=1)
__global__ void k_head(const float* __restrict__ h, const float* __restrict__ w,
                       const float* __restrict__ bias, float* __restrict__ out, int layer) {
    int idx = blockIdx.x * 256 + threadIdx.x;          // 16*64*512
    int l = idx & 511, o = (idx >> 9) & 63, b = idx >> 15;
    int ch = layer * 64 + o;
    float acc = bias[ch];
    for (int ci = 0; ci < 64; ++ci) {
        const float* s = h + (b * 64 + ci) * 512;
        const float* wr = w + (ch * 64 + ci) * 3;
#pragma unroll
        for (int j = 0; j < 3; ++j) {
            int p = l + j - 1;
            if (p >= 0 && p < 512) acc += s[p] * wr[j];
        }
    }
    out[idx] = acc;   // (b*64+o)*512 + l
}

// ---------------- convt_pre: lrelu then ConvTranspose1d(32->32, k=16, s=8, p=4)
__global__ void k_convt(const float* __restrict__ x, const float* __restrict__ w,
                        const float* __restrict__ bias, float* __restrict__ xx) {
    int idx = blockIdx.x * 256 + threadIdx.x;          // 16*32*4096
    int t = idx & 4095, co = (idx >> 12) & 31, b = idx >> 17;
    int m0 = (t + 4) & 7, s0 = (t + 4) >> 3;
    float acc = bias[co];
    for (int ci = 0; ci < 32; ++ci) {
        const float* xr = x + (b * 32 + ci) * 512;
        const float* wr = w + (ci * 32 + co) * 16;
        if (s0 < 512) acc += lrelu(xr[s0]) * wr[m0];
        if (s0 >= 1) acc += lrelu(xr[s0 - 1]) * wr[m0 + 8];
    }
    xx[idx] = acc;
}

// ---------------- dilated conv block: lrelu(conv(lrelu(xx), k=3, dil, pad=dil))
__global__ void k_cblock(const float* __restrict__ xx, const float* __restrict__ w,
                         const float* __restrict__ bias, float* __restrict__ cb,
                         int layer, int dil) {
    int idx = blockIdx.x * 256 + threadIdx.x;          // 16*32*4096
    int t = idx & 4095, ci = (idx >> 12) & 31, b = idx >> 17;
    float acc = bias[layer * 32 + ci];
    for (int c2 = 0; c2 < 32; ++c2) {
        const float* s = xx + (b * 32 + c2) * 4096;
        const float* wr = w + ((layer * 32 + ci) * 32 + c2) * 3;
#pragma unroll
        for (int j = 0; j < 3; ++j) {
            int p = t + (j - 1) * dil;
            if (p >= 0 && p < 4096) acc += lrelu(s[p]) * wr[j];
        }
    }
    cb[idx] = lrelu(acc);
}

// ---------------- weight pack (ONE layer): fp32 -> hi/lo bf16, MFMA A-frag order.
// Flat: (((c*24 + MT)*6 + ks)*64 + lane)*8 + j ; A[m=lane&15][k=quad*8+j].
// Row r = MT*16 + m; ik = r>>2 (=i*3+kk), oc = r&3;
// o = 32*(oc&1) + 2*c + (oc>>1); ch = (i*64+o)*3 + kk.
__global__ void k_pack_w2(const float* __restrict__ ker_w, ushort* __restrict__ Whi,
                          ushort* __restrict__ Wlo, int layer) {
    int g = blockIdx.x * 256 + threadIdx.x;            // < 147456
    int lane = g & 63;
    int g2 = g >> 6;
    int ks = g2 % 6;  int g3 = g2 / 6;
    int mt = g3 % 24; int c = g3 / 24;                 // c in [0,16)
    int m = lane & 15, quad = lane >> 4;
    int r = mt * 16 + m;
    int ik = r >> 2, oc = r & 3;
    int i = ik / 3, kk = ik - i * 3;
    int o = 32 * (oc & 1) + 2 * c + (oc >> 1);
    int ch = (i * 64 + o) * 3 + kk;
    const float* src = ker_w + ((size_t)(layer * 6144 + ch)) * 192 + ks * 32 + quad * 8;
    uint uh[4], ul[4];
#pragma unroll
    for (int t = 0; t < 4; ++t) {
        float f0 = src[2 * t], f1 = src[2 * t + 1];
        ushort h0 = f2bf(f0), h1 = f2bf(f1);
        ushort l0 = f2bf(f0 - bf2f(h0)), l1 = f2bf(f1 - bf2f(h1));
        uh[t] = (uint)h0 | ((uint)h1 << 16);
        ul[t] = (uint)l0 | ((uint)l1 << 16);
    }
    *reinterpret_cast<uint4*>(Whi + (size_t)g * 8) = make_uint4(uh[0], uh[1], uh[2], uh[3]);
    *reinterpret_cast<uint4*>(Wlo + (size_t)g * 8) = make_uint4(ul[0], ul[1], ul[2], ul[3]);
}

// ---------------- bias pack (ONE layer): ker_b -> chunk-row order Bpk[c][r]
__global__ void k_pack_b(const float* __restrict__ ker_b, float* __restrict__ Bpk,
                         int layer) {
    int idx = blockIdx.x * 256 + threadIdx.x;          // < 6144
    int c = idx / 384, r = idx - c * 384;
    int ik = r >> 2, oc = r & 3;
    int i = ik / 3, kk = ik - i * 3;
    int o = 32 * (oc & 1) + 2 * c + (oc >> 1);
    int ch = (i * 64 + o) * 3 + kk;
    Bpk[idx] = ker_b[layer * 6144 + ch];
}

// ---------------- fused: split-precision MFMA kernel-head GEMM + einsum + gate
// Block = (b, 32-l tile, quarter), 256 threads (4 waves). Chunk c: o in
// {2c,2c+1,32+2c,32+2c+1}. 12 passes/chunk; pass = 2 m-tiles x 2 n-tiles,
// wave w -> nt=w&1, mtl=w>>1 (ONE MFMA job/wave/pass). All fragments in LDS.
__global__ __launch_bounds__(256) void
k_lvc(const float* __restrict__ h, const float* __restrict__ cb,
      const float* __restrict__ kbL, const ushort* __restrict__ Whi,
      const ushort* __restrict__ Wlo, const float* __restrict__ Bpk,
      float* __restrict__ xx) {
    __shared__ ushort HfH[6144];        // 12288 B: ((nt*6+ks)*64+lane)*8+j
    __shared__ ushort HfL[6144];        // 12288 B
    __shared__ ushort WstHi[6144];      // 12288 B: ((mtl*6+ks)*64+lane)*8+j
    __shared__ ushort WstLo[6144];      // 12288 B
    __shared__ float kc[1024];          // 4096 B: kc[(ik_local*32+n)*4+oc]
    // total 53248 B -> 2 blocks/CU

    int tid = threadIdx.x;
    int qtr = blockIdx.x & 3;           // fixed quarter per XCD (%8 round-robin)
    int lt = (blockIdx.x >> 2) & 15;
    int b = blockIdx.x >> 6;
    int l0 = lt * 32;

    // ---- build h hi/lo B-fragments ONCE into LDS (flat fragment order).
    // B[k=quad*8+j][n=nt*16+n16]; value identical to R12's register build.
    for (int v = tid; v < 6144; v += 256) {
        int j = v & 7;
        int lane_ = (v >> 3) & 63;
        int r2 = v >> 9;                // nt_*6 + ks
        int ks = r2 % 6, nt_ = r2 / 6;
        int n = nt_ * 16 + (lane_ & 15);
        int cj = ks * 32 + (lane_ >> 4) * 8 + j;
        int ci = cj / 3, jt = cj - ci * 3;
        int p = l0 + n + jt - 1;
        float val = (p >= 0 && p < 512) ? h[(b * 64 + ci) * 512 + p] : 0.f;
        ushort hi = f2bf(val);
        HfH[v] = hi;
        HfL[v] = f2bf(val - bf2f(hi));
    }
    // (first pass's staging __syncthreads also orders these writes vs reads)

    int wave = tid >> 6, lane = tid & 63;
    int n16 = lane & 15, quad = lane >> 4;
    int nt = wave & 1;                  // this wave's n-tile
    int mtl = wave >> 1;                // this wave's local m-tile (0..1)

    const ushort* hfh = &HfH[(nt * 6) * 512 + lane * 8];
    const ushort* hfl = &HfL[(nt * 6) * 512 + lane * 8];
    const ushort* wsh = &WstHi[(mtl * 6) * 512 + lane * 8];
    const ushort* wsl = &WstLo[(mtl * 6) * 512 + lane * 8];

    int h8 = tid & 7, n2 = tid >> 3;    // phase-2: hop h8, location n2 in [0,32)
    int lg = l0 + n2;
    int tglob = lg * 8 + h8;
    const float* cbb = cb + b * 32 * 4096;
    const float* kbb = kbL + b * 64 * 512;
    float* xxb = xx + b * 32 * 4096;

    for (int cc = 0; cc < 4; ++cc) {
        int c = qtr * 4 + cc;
        float a0 = 0.f, a1 = 0.f, a2 = 0.f, a3 = 0.f;   // phase-2 partials
        for (int p = 0; p < 12; ++p) {
            // ---- stage this pass's 2-MT weight slice into LDS (768 uint4 each)
            {
                const uint4* srcH = reinterpret_cast<const uint4*>(
                    Whi + ((size_t)(c * 24 + p * 2) * 6) * 512);
                const uint4* srcL = reinterpret_cast<const uint4*>(
                    Wlo + ((size_t)(c * 24 + p * 2) * 6) * 512);
                uint4* dH = reinterpret_cast<uint4*>(WstHi);
                uint4* dL = reinterpret_cast<uint4*>(WstLo);
#pragma unroll
                for (int v = 0; v < 3; ++v) {
                    dH[tid + v * 256] = srcH[tid + v * 256];
                    dL[tid + v * 256] = srcL[tid + v * 256];
                }
            }
            __syncthreads();

            // ---- phase 1: one MFMA job per wave; all operands via ds_read.
            // unroll 2 is SAFE: ks feeds LDS addresses only (no reg arrays).
            {
                int MT = p * 2 + mtl;
                f32x4 acc = {0.f, 0.f, 0.f, 0.f};
#pragma unroll 2
                for (int ks = 0; ks < 6; ++ks) {
                    short8 whf = *reinterpret_cast<const short8*>(wsh + ks * 512);
                    short8 wlf = *reinterpret_cast<const short8*>(wsl + ks * 512);
                    short8 bhf = *reinterpret_cast<const short8*>(hfh + ks * 512);
                    short8 blf = *reinterpret_cast<const short8*>(hfl + ks * 512);
                    acc = __builtin_amdgcn_mfma_f32_16x16x32_bf16(whf, bhf, acc, 0, 0, 0);
                    acc = __builtin_amdgcn_mfma_f32_16x16x32_bf16(wlf, bhf, acc, 0, 0, 0);
                    acc = __builtin_amdgcn_mfma_f32_16x16x32_bf16(whf, blf, acc, 0, 0, 0);
                }
                acc += *reinterpret_cast<const f32x4*>(Bpk + c * 384 + MT * 16 + quad * 4);
                // D: col=lane&15 -> n16, row=quad*4+reg; ik_local = mtl*4+quad, oc=reg
                *reinterpret_cast<f32x4*>(
                    &kc[((mtl * 4 + quad) * 32 + nt * 16 + n16) * 4]) = acc;
            }
            __syncthreads();

            // ---- phase 2 partial: global ik = p*8 + ikk (ascending = R12 order)
#pragma unroll
            for (int ikk = 0; ikk < 8; ++ikk) {
                int ik = p * 8 + ikk;
                int i = ik / 3, kk = ik - i * 3;
                int tt = tglob + kk - 1;
                float xv = (tt >= 0 && tt < 4096) ? cbb[i * 4096 + tt] : 0.f;
                float4 kv = *reinterpret_cast<const float4*>(&kc[(ikk * 32 + n2) * 4]);
                a0 += kv.x * xv; a1 += kv.y * xv; a2 += kv.z * xv; a3 += kv.w * xv;
            }
            __syncthreads();   // Wst/kc reused by next pass
        }
        // ---- gate: oc {0,1,2,3} -> o {2c, 32+2c, 2c+1, 32+2c+1}
        {
            float pa = a0 + kbb[(2 * c) * 512 + lg];
            float pb = a1 + kbb[(32 + 2 * c) * 512 + lg];
            float g = (1.f / (1.f + expf(-pa))) * tanhf(pb);
            xxb[(2 * c) * 4096 + tglob] += g;
            pa = a2 + kbb[(2 * c + 1) * 512 + lg];
            pb = a3 + kbb[(32 + 2 * c + 1) * 512 + lg];
            g = (1.f / (1.f + expf(-pa))) * tanhf(pb);
            xxb[(2 * c + 1) * 4096 + tglob] += g;
        }
    }
}

extern "C" void kernel_launch(void* const* d_in, const int* in_sizes, int n_in,
                              void* d_out, int out_size, void* d_ws, size_t ws_size,
                              hipStream_t stream) {
    const float* x      = (const float*)d_in[0];
    const float* c      = (const float*)d_in[1];
    const float* in_w   = (const float*)d_in[2];
    const float* in_b   = (const float*)d_in[3];
    const float* res_ws = (const float*)d_in[4];
    const float* res_bs = (const float*)d_in[5];
    const float* ker_w  = (const float*)d_in[6];
    const float* ker_b  = (const float*)d_in[7];
    const float* bias_w = (const float*)d_in[8];
    const float* bias_b = (const float*)d_in[9];
    const float* ct_w   = (const float*)d_in[10];
    const float* ct_b   = (const float*)d_in[11];
    const float* cb_ws  = (const float*)d_in[12];
    const float* cb_bs  = (const float*)d_in[13];

    float* ws   = (float*)d_ws;
    float* h    = ws;                         // [0, 524288)
    float* kbL  = ws + 524288;                // [524288, 1048576)
    float* tmp  = ws + 1048576;               // [1048576, 1572864)
    float* cb   = ws + 1572864;               // [1572864, 3670016)
    ushort* Whi = (ushort*)(ws + 3670016);    // [3670016, 4259840)
    ushort* Wlo = (ushort*)(ws + 4259840);    // [4259840, 4849664)
    float* Bpk  = ws + 4849664;               // [4849664, 4855808)
    // high-water 19.42 MB (< 20.97 MB proven by R2's pass)
    float* xx   = (float*)d_out;              // state tensor lives in d_out

    k_pred_in<<<2048, 256, 0, stream>>>(c, in_w, in_b, h);
    for (int j = 0; j < 3; ++j) {
        k_res<<<2048, 256, 0, stream>>>(h,   res_ws + (j * 2 + 0) * 64 * 64 * 3,
                                        res_bs + (j * 2 + 0) * 64, tmp, nullptr);
        k_res<<<2048, 256, 0, stream>>>(tmp, res_ws + (j * 2 + 1) * 64 * 64 * 3,
                                        res_bs + (j * 2 + 1) * 64, h, h);
    }
    k_convt<<<8192, 256, 0, stream>>>(x, ct_w, ct_b, xx);

    const int dils[4] = {1, 3, 9, 27};
    for (int L = 0; L < 4; ++L) {
        k_head<<<2048, 256, 0, stream>>>(h, bias_w, bias_b, kbL, L);
        k_pack_w2<<<576, 256, 0, stream>>>(ker_w, Whi, Wlo, L);
        k_pack_b<<<24, 256, 0, stream>>>(ker_b, Bpk, L);
        k_cblock<<<8192, 256, 0, stream>>>(xx, cb_ws, cb_bs, cb, L, dils[L]);
        k_lvc<<<1024, 256, 0, stream>>>(h, cb, kbL, Whi, Wlo, Bpk, xx);
    }
}

// Round 14
// 1551.241 us; speedup vs baseline: 6.7295x; 1.2022x over previous
//
#include <hip/hip_runtime.h>
#include <math.h>

// LVCBlock forward, MI355X (gfx950).
// Shapes: B=16, CIN=32, CCOND=100, Lc=512, HOP=8, T=4096, HID=64, NL=4, K=3, COUT=64.
// ALL inputs and the output are float32.
//
// R14 vs R13 (passed 0.03125, k_lvc 203us, LDS-pipe-bound ~150us of 203,
// 3 barriers/pass, 25% occupancy):
//  (1) no weight LDS staging: weight fragments read DIRECT from global
//      (L2-resident, qtr<->XCD pinned) in the unroll-2 loop (bounded
//      transients; R8/R13 precedent -> no spill).
//  (2) pass = 4 m-tiles; wave does 2 MT sharing one h-fragment ds_read.
//  (3) kc double-buffered -> ONE barrier/pass (24/block vs 144).
//  (4) LDS 40KB (Hf 24 + kc 2x8) -> 4 blocks/CU = 50% occupancy.
//  (5) cb padded (stride 4098 + guard zeros) -> no phase-2 bounds checks;
//      k_pack_b merged into k_pack (saves 4 dispatches).
// Split-precision MFMA math bit-identical to R13 (absmax must stay 0.03125).

#define DEV __device__ __forceinline__

typedef unsigned short ushort;
typedef unsigned int uint;
typedef __attribute__((ext_vector_type(8))) short short8;   // 8 bf16 (4 VGPRs)
typedef __attribute__((ext_vector_type(4))) float f32x4;

DEV float lrelu(float x) { return x > 0.f ? x : 0.2f * x; }

DEV ushort f2bf(float f) {                     // fp32 -> bf16 bits, RNE
    uint u = __float_as_uint(f);
    return (ushort)((u + 0x7fffu + ((u >> 16) & 1u)) >> 16);
}
DEV float bf2f(ushort b) { return __uint_as_float(((uint)b) << 16); }

// ---------------- kernel predictor: input conv (100->64, k=5, pad=2) + lrelu
__global__ void k_pred_in(const float* __restrict__ c, const float* __restrict__ w,
                          const float* __restrict__ bias, float* __restrict__ h) {
    int idx = blockIdx.x * 256 + threadIdx.x;          // 16*64*512
    int l = idx & 511, co = (idx >> 9) & 63, b = idx >> 15;
    float acc = bias[co];
    for (int ci = 0; ci < 100; ++ci) {
        const float* crow = c + (b * 100 + ci) * 512;
        const float* wrow = w + (co * 100 + ci) * 5;
#pragma unroll
        for (int j = 0; j < 5; ++j) {
            int p = l + j - 2;
            if (p >= 0 && p < 512) acc += crow[p] * wrow[j];
        }
    }
    h[idx] = lrelu(acc);
}

// ---------------- residual conv (64->64, k=3, pad=1) + lrelu, optional accumulate
__global__ void k_res(const float* __restrict__ src, const float* __restrict__ w,
                      const float* __restrict__ bias, float* __restrict__ dst,
                      const float* __restrict__ accum) {
    int idx = blockIdx.x * 256 + threadIdx.x;          // 16*64*512
    int l = idx & 511, co = (idx >> 9) & 63, b = idx >> 15;
    float acc = bias[co];
    for (int ci = 0; ci < 64; ++ci) {
        const float* s = src + (b * 64 + ci) * 512;
        const float* wr = w + (co * 64 + ci) * 3;
#pragma unroll
        for (int j = 0; j < 3; ++j) {
            int p = l + j - 1;
            if (p >= 0 && p < 512) acc += s[p] * wr[j];
        }
    }
    float v = lrelu(acc);
    dst[idx] = accum ? accum[idx] + v : v;
}

// ---------------- bias head, ONE layer's 64 channels (k=3, pad=1)
__global__ void k_head(const float* __restrict__ h, const float* __restrict__ w,
                       const float* __restrict__ bias, float* __restrict__ out, int layer) {
    int idx = blockIdx.x * 256 + threadIdx.x;          // 16*64*512
    int l = idx & 511, o = (idx >> 9) & 63, b = idx >> 15;
    int ch = layer * 64 + o;
    float acc = bias[ch];
    for (int ci = 0; ci < 64; ++ci) {
        const float* s = h + (b * 64 + ci) * 512;
        const float* wr = w + (ch * 64 + ci) * 3;
#pragma unroll
        for (int j = 0; j < 3; ++j) {
            int p = l + j - 1;
            if (p >= 0 && p < 512) acc += s[p] * wr[j];
        }
    }
    out[idx] = acc;   // (b*64+o)*512 + l
}

// ---------------- convt_pre: lrelu then ConvTranspose1d(32->32, k=16, s=8, p=4)
__global__ void k_convt(const float* __restrict__ x, const float* __restrict__ w,
                        const float* __restrict__ bias, float* __restrict__ xx) {
    int idx = blockIdx.x * 256 + threadIdx.x;          // 16*32*4096
    int t = idx & 4095, co = (idx >> 12) & 31, b = idx >> 17;
    int m0 = (t + 4) & 7, s0 = (t + 4) >> 3;
    float acc = bias[co];
    for (int ci = 0; ci < 32; ++ci) {
        const float* xr = x + (b * 32 + ci) * 512;
        const float* wr = w + (ci * 32 + co) * 16;
        if (s0 < 512) acc += lrelu(xr[s0]) * wr[m0];
        if (s0 >= 1) acc += lrelu(xr[s0 - 1]) * wr[m0 + 8];
    }
    xx[idx] = acc;
}

// ---------------- dilated conv block -> PADDED cb (stride 4098, guard zeros)
__global__ void k_cblock(const float* __restrict__ xx, const float* __restrict__ w,
                         const float* __restrict__ bias, float* __restrict__ cbp,
                         int layer, int dil) {
    int idx = blockIdx.x * 256 + threadIdx.x;          // 16*32*4096
    int t = idx & 4095, ci = (idx >> 12) & 31, b = idx >> 17;
    float acc = bias[layer * 32 + ci];
    for (int c2 = 0; c2 < 32; ++c2) {
        const float* s = xx + (b * 32 + c2) * 4096;
        const float* wr = w + ((layer * 32 + ci) * 32 + c2) * 3;
#pragma unroll
        for (int j = 0; j < 3; ++j) {
            int p = t + (j - 1) * dil;
            if (p >= 0 && p < 4096) acc += lrelu(s[p]) * wr[j];
        }
    }
    float* row = cbp + (size_t)(b * 32 + ci) * 4098 + 1;
    row[t] = lrelu(acc);
    if (t == 0) row[-1] = 0.f;          // guard cells (rewritten every dispatch;
    if (t == 4095) row[4096] = 0.f;     //  ws is re-poisoned before each launch)
}

// ---------------- pack (ONE layer): weights fp32 -> hi/lo bf16 in MFMA A-frag
// order, bias -> chunk-row order. Block 576 handles the bias.
// W flat: (((c*24 + MT)*6 + ks)*64 + lane)*8 + j ; A[m=lane&15][k=quad*8+j].
// Row r = MT*16 + m; ik = r>>2 (=i*3+kk), oc = r&3;
// o = 32*(oc&1) + 2*c + (oc>>1); ch = (i*64+o)*3 + kk.
__global__ void k_pack(const float* __restrict__ ker_w, const float* __restrict__ ker_b,
                       ushort* __restrict__ Whi, ushort* __restrict__ Wlo,
                       float* __restrict__ Bpk, int layer) {
    if (blockIdx.x == 576) {            // bias pack: 6144 entries
        for (int idx = threadIdx.x; idx < 6144; idx += 256) {
            int c = idx / 384, r = idx - c * 384;
            int ik = r >> 2, oc = r & 3;
            int i = ik / 3, kk = ik - i * 3;
            int o = 32 * (oc & 1) + 2 * c + (oc >> 1);
            Bpk[idx] = ker_b[layer * 6144 + (i * 64 + o) * 3 + kk];
        }
        return;
    }
    int g = blockIdx.x * 256 + threadIdx.x;            // < 147456
    int lane = g & 63;
    int g2 = g >> 6;
    int ks = g2 % 6;  int g3 = g2 / 6;
    int mt = g3 % 24; int c = g3 / 24;                 // c in [0,16)
    int m = lane & 15, quad = lane >> 4;
    int r = mt * 16 + m;
    int ik = r >> 2, oc = r & 3;
    int i = ik / 3, kk = ik - i * 3;
    int o = 32 * (oc & 1) + 2 * c + (oc >> 1);
    int ch = (i * 64 + o) * 3 + kk;
    const float* src = ker_w + ((size_t)(layer * 6144 + ch)) * 192 + ks * 32 + quad * 8;
    uint uh[4], ul[4];
#pragma unroll
    for (int t = 0; t < 4; ++t) {
        float f0 = src[2 * t], f1 = src[2 * t + 1];
        ushort h0 = f2bf(f0), h1 = f2bf(f1);
        ushort l0 = f2bf(f0 - bf2f(h0)), l1 = f2bf(f1 - bf2f(h1));
        uh[t] = (uint)h0 | ((uint)h1 << 16);
        ul[t] = (uint)l0 | ((uint)l1 << 16);
    }
    *reinterpret_cast<uint4*>(Whi + (size_t)g * 8) = make_uint4(uh[0], uh[1], uh[2], uh[3]);
    *reinterpret_cast<uint4*>(Wlo + (size_t)g * 8) = make_uint4(ul[0], ul[1], ul[2], ul[3]);
}

// ---------------- fused: split-precision MFMA kernel-head GEMM + einsum + gate
// Block = (b, 32-l tile, quarter), 256 threads (4 waves). Chunk c: o in
// {2c,2c+1,32+2c,32+2c+1}. 6 passes/chunk; pass = 4 m-tiles x 2 n-tiles;
// wave w -> nt=w&1, 2 MT jobs (w>>1)*2+{0,1} sharing one h-fragment read.
// Weights direct from global (L2); h fragments in LDS; kc double-buffered,
// ONE barrier per pass.
__global__ __launch_bounds__(256) void
k_lvc(const float* __restrict__ h, const float* __restrict__ cbp,
      const float* __restrict__ kbL, const ushort* __restrict__ Whi,
      const ushort* __restrict__ Wlo, const float* __restrict__ Bpk,
      float* __restrict__ xx) {
    __shared__ ushort HfH[6144];        // 12288 B: ((nt*6+ks)*64+lane)*8+j
    __shared__ ushort HfL[6144];        // 12288 B
    __shared__ float kc[2 * 2048];      // 16384 B: dbuf, kc[(ik_local*32+n)*4+oc]
    // total 40960 B -> 4 blocks/CU

    int tid = threadIdx.x;
    int qtr = blockIdx.x & 3;           // fixed quarter per XCD (%8 round-robin)
    int lt = (blockIdx.x >> 2) & 15;
    int b = blockIdx.x >> 6;
    int l0 = lt * 32;

    // ---- build h hi/lo B-fragments ONCE into LDS (flat fragment order).
    for (int v = tid; v < 6144; v += 256) {
        int j = v & 7;
        int lane_ = (v >> 3) & 63;
        int r2 = v >> 9;                // nt_*6 + ks
        int ks = r2 % 6, nt_ = r2 / 6;
        int n = nt_ * 16 + (lane_ & 15);
        int cj = ks * 32 + (lane_ >> 4) * 8 + j;
        int ci = cj / 3, jt = cj - ci * 3;
        int p = l0 + n + jt - 1;
        float val = (p >= 0 && p < 512) ? h[(b * 64 + ci) * 512 + p] : 0.f;
        ushort hi = f2bf(val);
        HfH[v] = hi;
        HfL[v] = f2bf(val - bf2f(hi));
    }
    __syncthreads();

    int wave = tid >> 6, lane = tid & 63;
    int n16 = lane & 15, quad = lane >> 4;
    int nt = wave & 1;                  // this wave's n-tile
    int mt0 = (wave >> 1) * 2;          // this wave's 2 local m-tiles

    const ushort* hfh = &HfH[(nt * 6) * 512 + lane * 8];
    const ushort* hfl = &HfL[(nt * 6) * 512 + lane * 8];

    int h8 = tid & 7, n2 = tid >> 3;    // phase-2: hop h8, location n2 in [0,32)
    int lg = l0 + n2;
    int tglob = lg * 8 + h8;
    const float* cbb = cbp + (size_t)b * 32 * 4098;
    const float* kbb = kbL + b * 64 * 512;
    float* xxb = xx + b * 32 * 4096;

    for (int cc = 0; cc < 4; ++cc) {
        int c = qtr * 4 + cc;
        float a0 = 0.f, a1 = 0.f, a2 = 0.f, a3 = 0.f;   // phase-2 partials
        for (int p = 0; p < 6; ++p) {
            float* kcp = kc + (p & 1) * 2048;
            // ---- phase 1: 2 MT jobs per wave, shared h fragments; weights
            // direct from global (b128 coalesced, L2-resident quarter slice).
            {
                int MT0 = p * 4 + mt0;
                const ushort* wh0 = Whi + (((size_t)(c * 24 + MT0) * 6) * 64 + lane) * 8;
                const ushort* wl0 = Wlo + (((size_t)(c * 24 + MT0) * 6) * 64 + lane) * 8;
                f32x4 acc0 = {0.f, 0.f, 0.f, 0.f};
                f32x4 acc1 = {0.f, 0.f, 0.f, 0.f};
#pragma unroll 2
                for (int ks = 0; ks < 6; ++ks) {
                    short8 bhf = *reinterpret_cast<const short8*>(hfh + ks * 512);
                    short8 blf = *reinterpret_cast<const short8*>(hfl + ks * 512);
                    short8 w0h = *reinterpret_cast<const short8*>(wh0 + ks * 512);
                    short8 w0l = *reinterpret_cast<const short8*>(wl0 + ks * 512);
                    acc0 = __builtin_amdgcn_mfma_f32_16x16x32_bf16(w0h, bhf, acc0, 0, 0, 0);
                    acc0 = __builtin_amdgcn_mfma_f32_16x16x32_bf16(w0l, bhf, acc0, 0, 0, 0);
                    acc0 = __builtin_amdgcn_mfma_f32_16x16x32_bf16(w0h, blf, acc0, 0, 0, 0);
                    short8 w1h = *reinterpret_cast<const short8*>(wh0 + 3072 + ks * 512);
                    short8 w1l = *reinterpret_cast<const short8*>(wl0 + 3072 + ks * 512);
                    acc1 = __builtin_amdgcn_mfma_f32_16x16x32_bf16(w1h, bhf, acc1, 0, 0, 0);
                    acc1 = __builtin_amdgcn_mfma_f32_16x16x32_bf16(w1l, bhf, acc1, 0, 0, 0);
                    acc1 = __builtin_amdgcn_mfma_f32_16x16x32_bf16(w1h, blf, acc1, 0, 0, 0);
                }
                acc0 += *reinterpret_cast<const f32x4*>(Bpk + c * 384 + MT0 * 16 + quad * 4);
                acc1 += *reinterpret_cast<const f32x4*>(Bpk + c * 384 + (MT0 + 1) * 16 + quad * 4);
                // D: col=lane&15 -> n16, row=quad*4+reg; ik_local = lmt*4+quad, oc=reg
                *reinterpret_cast<f32x4*>(
                    &kcp[((mt0 * 4 + quad) * 32 + nt * 16 + n16) * 4]) = acc0;
                *reinterpret_cast<f32x4*>(
                    &kcp[(((mt0 + 1) * 4 + quad) * 32 + nt * 16 + n16) * 4]) = acc1;
            }
            __syncthreads();            // kc(p) complete; also licenses phase1(p+1)->other buf

            // ---- phase 2 partial: global ik = p*16 + ikk (ascending; padded cb)
#pragma unroll
            for (int ikk = 0; ikk < 16; ++ikk) {
                int ik = p * 16 + ikk;
                int i = ik / 3, kk = ik - i * 3;
                float xv = cbb[(size_t)i * 4098 + tglob + kk];
                float4 kv = *reinterpret_cast<const float4*>(&kcp[(ikk * 32 + n2) * 4]);
                a0 += kv.x * xv; a1 += kv.y * xv; a2 += kv.z * xv; a3 += kv.w * xv;
            }
            // no trailing barrier: next pass writes the other kc buffer, and its
            // barrier (before phase2 p+1) orders everything (max skew = 1 pass).
        }
        // ---- gate: oc {0,1,2,3} -> o {2c, 32+2c, 2c+1, 32+2c+1}
        {
            float pa = a0 + kbb[(2 * c) * 512 + lg];
            float pb = a1 + kbb[(32 + 2 * c) * 512 + lg];
            float g = (1.f / (1.f + expf(-pa))) * tanhf(pb);
            xxb[(2 * c) * 4096 + tglob] += g;
            pa = a2 + kbb[(2 * c + 1) * 512 + lg];
            pb = a3 + kbb[(32 + 2 * c + 1) * 512 + lg];
            g = (1.f / (1.f + expf(-pa))) * tanhf(pb);
            xxb[(2 * c + 1) * 4096 + tglob] += g;
        }
    }
}

extern "C" void kernel_launch(void* const* d_in, const int* in_sizes, int n_in,
                              void* d_out, int out_size, void* d_ws, size_t ws_size,
                              hipStream_t stream) {
    const float* x      = (const float*)d_in[0];
    const float* c      = (const float*)d_in[1];
    const float* in_w   = (const float*)d_in[2];
    const float* in_b   = (const float*)d_in[3];
    const float* res_ws = (const float*)d_in[4];
    const float* res_bs = (const float*)d_in[5];
    const float* ker_w  = (const float*)d_in[6];
    const float* ker_b  = (const float*)d_in[7];
    const float* bias_w = (const float*)d_in[8];
    const float* bias_b = (const float*)d_in[9];
    const float* ct_w   = (const float*)d_in[10];
    const float* ct_b   = (const float*)d_in[11];
    const float* cb_ws  = (const float*)d_in[12];
    const float* cb_bs  = (const float*)d_in[13];

    float* ws   = (float*)d_ws;
    float* h    = ws;                         // [0, 524288)
    float* kbL  = ws + 524288;                // [524288, 1048576)
    float* tmp  = ws + 1048576;               // [1048576, 1572864)
    float* cbp  = ws + 1572864;               // [1572864, 3671040)  16*32*4098 padded
    ushort* Whi = (ushort*)(ws + 3671040);    // [3671040, 4260864)
    ushort* Wlo = (ushort*)(ws + 4260864);    // [4260864, 4850688)
    float* Bpk  = ws + 4850688;               // [4850688, 4856832)
    // high-water 19.43 MB (< 20.97 MB proven by R2's pass)
    float* xx   = (float*)d_out;              // state tensor lives in d_out

    k_pred_in<<<2048, 256, 0, stream>>>(c, in_w, in_b, h);
    for (int j = 0; j < 3; ++j) {
        k_res<<<2048, 256, 0, stream>>>(h,   res_ws + (j * 2 + 0) * 64 * 64 * 3,
                                        res_bs + (j * 2 + 0) * 64, tmp, nullptr);
        k_res<<<2048, 256, 0, stream>>>(tmp, res_ws + (j * 2 + 1) * 64 * 64 * 3,
                                        res_bs + (j * 2 + 1) * 64, h, h);
    }
    k_convt<<<8192, 256, 0, stream>>>(x, ct_w, ct_b, xx);

    const int dils[4] = {1, 3, 9, 27};
    for (int L = 0; L < 4; ++L) {
        k_head<<<2048, 256, 0, stream>>>(h, bias_w, bias_b, kbL, L);
        k_pack<<<577, 256, 0, stream>>>(ker_w, ker_b, Whi, Wlo, Bpk, L);
        k_cblock<<<8192, 256, 0, stream>>>(xx, cb_ws, cb_bs, cbp, L, dils[L]);
        k_lvc<<<1024, 256, 0, stream>>>(h, cbp, kbL, Whi, Wlo, Bpk, xx);
    }
}